// Round 5
// baseline (564.988 us; speedup 1.0000x reference)
//
#include <hip/hip_runtime.h>
#include <cstddef>
#include <cstdint>

#define TT 2048
#define EE 1024
#define HH 16
#define NSP 2

typedef unsigned short ushort;
typedef unsigned int uint;
typedef __attribute__((ext_vector_type(8))) short short8;
typedef __attribute__((ext_vector_type(8))) _Float16 half8;
typedef __attribute__((ext_vector_type(4))) float f32x4;
typedef __attribute__((ext_vector_type(4))) ushort ushort4v;

__device__ __forceinline__ ushort f2bf(float f) {
  uint u = __builtin_bit_cast(uint, f);
  u = (u + 0x7FFFu + ((u >> 16) & 1u)) >> 16;
  return (ushort)u;
}
__device__ __forceinline__ float bf2f(ushort h) {
  return __builtin_bit_cast(float, (uint)h << 16);
}
__device__ __forceinline__ ushort f2h(float f) {
  return __builtin_bit_cast(ushort, (_Float16)f);
}

// async global->LDS, 16B per lane; lds dest = wave-uniform base + lane*16
__device__ __forceinline__ void async16(ushort* lds, const ushort* g) {
  __builtin_amdgcn_global_load_lds(
      reinterpret_cast<const __attribute__((address_space(1))) void*>(
          reinterpret_cast<uintptr_t>(g)),
      reinterpret_cast<__attribute__((address_space(3))) void*>(
          static_cast<unsigned int>(reinterpret_cast<uintptr_t>(lds))),
      16, 0, 0);
}

// ---------------------------------------------------------------------------
// Fused: x (T,E) fp32 -> xbf (bf16), xh (f16), xT (E,T fp32). Zeroes snorm.
// ---------------------------------------------------------------------------
__global__ __launch_bounds__(256) void cvt_xt(
    const float* __restrict__ in, ushort* __restrict__ obf,
    ushort* __restrict__ oh, float* __restrict__ outT,
    float* __restrict__ snorm)
{
  __shared__ float tile[32][33];
  if (blockIdx.x == 0 && blockIdx.y == 0) {
    for (int i = threadIdx.x; i < TT; i += 256) snorm[i] = 0.f;
  }
  const int bn = blockIdx.x * 32;   // col base (E)
  const int bm = blockIdx.y * 32;   // row base (T)
  const int c4 = (threadIdx.x & 7) * 4;
  const int r  = threadIdx.x >> 3;  // 0..31
  const size_t off = (size_t)(bm + r) * EE + bn + c4;
  float4 v = *(const float4*)(in + off);
  tile[r][c4 + 0] = v.x; tile[r][c4 + 1] = v.y;
  tile[r][c4 + 2] = v.z; tile[r][c4 + 3] = v.w;
  ushort4v b, h;
  b.x = f2bf(v.x); b.y = f2bf(v.y); b.z = f2bf(v.z); b.w = f2bf(v.w);
  h.x = f2h(v.x);  h.y = f2h(v.y);  h.z = f2h(v.z);  h.w = f2h(v.w);
  *(ushort4v*)(obf + off) = b;
  *(ushort4v*)(oh + off) = h;
  __syncthreads();
  const int t4 = (threadIdx.x & 7) * 4;   // t offset within tile
  const int e  = threadIdx.x >> 3;        // e offset within tile
  float4 w;
  w.x = tile[t4 + 0][e]; w.y = tile[t4 + 1][e];
  w.z = tile[t4 + 2][e]; w.w = tile[t4 + 3][e];
  *(float4*)(outT + (size_t)(bn + e) * TT + bm + t4) = w;
}

__global__ __launch_bounds__(256) void cvt_w_k(
    const float* __restrict__ s0, const float* __restrict__ s1,
    const float* __restrict__ s2, const float* __restrict__ s3,
    const float* __restrict__ s4, const float* __restrict__ s5,
    ushort* __restrict__ d0, ushort* __restrict__ d1,
    ushort* __restrict__ d2, ushort* __restrict__ d3,
    ushort* __restrict__ d4, ushort* __restrict__ d5, int n) {
  const int which = blockIdx.y;
  const float* src; ushort* dst;
  switch (which) {
    case 0: src = s0; dst = d0; break;
    case 1: src = s1; dst = d1; break;
    case 2: src = s2; dst = d2; break;
    case 3: src = s3; dst = d3; break;
    case 4: src = s4; dst = d4; break;
    default: src = s5; dst = d5; break;
  }
  int i = (blockIdx.x * 256 + threadIdx.x) * 4;
  if (i >= n) return;
  float4 v = *(const float4*)(src + i);
  ushort4v o;
  if (which == 5) {
    o.x = f2h(v.x); o.y = f2h(v.y); o.z = f2h(v.z); o.w = f2h(v.w);
  } else {
    o.x = f2bf(v.x); o.y = f2bf(v.y); o.z = f2bf(v.z); o.w = f2bf(v.w);
  }
  *(ushort4v*)(dst + i) = o;
}

// ---------------------------------------------------------------------------
// Merged 5-way projection GEMM (round-7 structure, unchanged):
//   BK=64, dbuf LDS, one barrier per K-step, XOR-swizzled LDS.
// z=0..3: bf16 x@W^T -> qhb/khb(OM1 bf16), vtb(OM2 f16), rvhb(OM1 bf16)
// z=4:    f16  xh@wjh^T -> echoT (E,T bf16, OM3) + snorm row norms
// ---------------------------------------------------------------------------
__global__ __launch_bounds__(256) void proj5(
    const ushort* __restrict__ Abf, const ushort* __restrict__ Ah,
    const ushort* __restrict__ B0, const ushort* __restrict__ B1,
    const ushort* __restrict__ B2, const ushort* __restrict__ B3,
    const ushort* __restrict__ B4,
    ushort* __restrict__ C0, ushort* __restrict__ C1,
    ushort* __restrict__ C2, ushort* __restrict__ C3,
    ushort* __restrict__ C4, float* __restrict__ snorm,
    int M, int N, int K)
{
  const ushort* A; const ushort* B; ushort* C; int om;
  switch (blockIdx.z) {
    case 0: A = Abf; B = B0; C = C0; om = 1; break;
    case 1: A = Abf; B = B1; C = C1; om = 1; break;
    case 2: A = Abf; B = B2; C = C2; om = 2; break;
    case 3: A = Abf; B = B3; C = C3; om = 1; break;
    default: A = Ah; B = B4; C = C4; om = 3; break;
  }
  const bool f16 = (blockIdx.z == 4);
  __shared__ __align__(16) ushort As[2][128 * 64];
  __shared__ __align__(16) ushort Bs[2][128 * 64];
  const int tid = threadIdx.x;
  const int m0 = blockIdx.y * 128, n0 = blockIdx.x * 128;
  const int w = tid >> 6, lane = tid & 63;
  const int wr = w >> 1, wc = w & 1;
  const int lr = lane & 15, lk = lane >> 4;
  const int srow = lane >> 3;                   // 0..7 within 8-row stripe
  const int scol = ((lane & 7) ^ srow) * 8;     // pre-swizzled source granule
  const ushort* AgL = A + (size_t)(m0 + w * 32 + srow) * K + scol;
  const ushort* BgL = B + (size_t)(n0 + w * 32 + srow) * K + scol;
  const int sbase = (w * 32) * 64;
  const int s0 = (lk ^ (lr & 7)) * 8;
  f32x4 acc[4][4] = {};
  const int NT = K >> 6;
#pragma unroll
  for (int c = 0; c < 4; ++c) {
    async16(&As[0][sbase + c * 8 * 64], AgL + (size_t)c * 8 * K);
    async16(&Bs[0][sbase + c * 8 * 64], BgL + (size_t)c * 8 * K);
  }
  __syncthreads();
  for (int kt = 0; kt < NT; ++kt) {
    const int cur = kt & 1;
    if (kt + 1 < NT) {
      const int kn = (kt + 1) << 6;
#pragma unroll
      for (int c = 0; c < 4; ++c) {
        async16(&As[cur ^ 1][sbase + c * 8 * 64], AgL + (size_t)c * 8 * K + kn);
        async16(&Bs[cur ^ 1][sbase + c * 8 * 64], BgL + (size_t)c * 8 * K + kn);
      }
    }
    short8 a0[4], a1[4], b0[4], b1[4];
#pragma unroll
    for (int i = 0; i < 4; ++i) {
      const ushort* p = &As[cur][(wr * 64 + i * 16 + lr) * 64];
      a0[i] = *(const short8*)(p + s0);
      a1[i] = *(const short8*)(p + (s0 ^ 32));
    }
#pragma unroll
    for (int j = 0; j < 4; ++j) {
      const ushort* p = &Bs[cur][(wc * 64 + j * 16 + lr) * 64];
      b0[j] = *(const short8*)(p + s0);
      b1[j] = *(const short8*)(p + (s0 ^ 32));
    }
    if (f16) {
#pragma unroll
      for (int i = 0; i < 4; ++i)
#pragma unroll
        for (int j = 0; j < 4; ++j) {
          acc[i][j] = __builtin_amdgcn_mfma_f32_16x16x32_f16(
              __builtin_bit_cast(half8, a0[i]), __builtin_bit_cast(half8, b0[j]),
              acc[i][j], 0, 0, 0);
          acc[i][j] = __builtin_amdgcn_mfma_f32_16x16x32_f16(
              __builtin_bit_cast(half8, a1[i]), __builtin_bit_cast(half8, b1[j]),
              acc[i][j], 0, 0, 0);
        }
    } else {
#pragma unroll
      for (int i = 0; i < 4; ++i)
#pragma unroll
        for (int j = 0; j < 4; ++j) {
          acc[i][j] = __builtin_amdgcn_mfma_f32_16x16x32_bf16(
              a0[i], b0[j], acc[i][j], 0, 0, 0);
          acc[i][j] = __builtin_amdgcn_mfma_f32_16x16x32_bf16(
              a1[i], b1[j], acc[i][j], 0, 0, 0);
        }
    }
    __syncthreads();
  }
#pragma unroll
  for (int i = 0; i < 4; ++i)
#pragma unroll
    for (int r = 0; r < 4; ++r) {
      int row = m0 + wr * 64 + i * 16 + lk * 4 + r;
#pragma unroll
      for (int j = 0; j < 4; ++j) {
        int col = n0 + wc * 64 + j * 16 + lr;
        ushort v = (om == 2) ? f2h(acc[i][j][r]) : f2bf(acc[i][j][r]);
        if (om == 1)
          C[((size_t)(col >> 6) * M + row) * 64 + (col & 63)] = v;
        else if (om == 2)
          C[(size_t)(col >> 6) * 64 * M + (size_t)(col & 63) * M + row] = v;
        else
          C[(size_t)col * M + row] = v;
      }
    }
  if (om == 3) {
#pragma unroll
    for (int i = 0; i < 4; ++i)
#pragma unroll
      for (int r = 0; r < 4; ++r) {
        float p = 0.f;
#pragma unroll
        for (int j = 0; j < 4; ++j) p += acc[i][j][r] * acc[i][j][r];
        p += __shfl_xor(p, 1); p += __shfl_xor(p, 2);
        p += __shfl_xor(p, 4); p += __shfl_xor(p, 8);
        if (lr == 0)
          atomicAdd(&snorm[m0 + wr * 64 + i * 16 + lk * 4 + r], p);
      }
  }
}

// ---------------------------------------------------------------------------
// Generic MFMA GEMM (janus / out), fp32 out (round-7 structure, unchanged).
// ---------------------------------------------------------------------------
template<bool CZ>
__global__ __launch_bounds__(256) void gemm_mfma(
    const ushort* __restrict__ A, const ushort* __restrict__ B,
    float* __restrict__ Cp, int M, int N, int K)
{
  __shared__ __align__(16) ushort As[2][128 * 64];
  __shared__ __align__(16) ushort Bs[2][128 * 64];
  const int tid = threadIdx.x;
  const int m0 = blockIdx.y * 128, n0 = blockIdx.x * 128;
  const int w = tid >> 6, lane = tid & 63;
  const int wr = w >> 1, wc = w & 1;
  const int lr = lane & 15, lk = lane >> 4;
  const int srow = lane >> 3;
  const int scol = ((lane & 7) ^ srow) * 8;
  const ushort* AgL = A + (size_t)(m0 + w * 32 + srow) * K + scol;
  const ushort* BgL = B + (size_t)(n0 + w * 32 + srow) * K + scol;
  const int sbase = (w * 32) * 64;
  const int s0 = (lk ^ (lr & 7)) * 8;
  f32x4 acc[4][4] = {};
  const int Keff = CZ ? (K < m0 + 128 ? K : m0 + 128) : K;
  const int NT = Keff >> 6;
#pragma unroll
  for (int c = 0; c < 4; ++c) {
    async16(&As[0][sbase + c * 8 * 64], AgL + (size_t)c * 8 * K);
    async16(&Bs[0][sbase + c * 8 * 64], BgL + (size_t)c * 8 * K);
  }
  __syncthreads();
  for (int kt = 0; kt < NT; ++kt) {
    const int cur = kt & 1;
    if (kt + 1 < NT) {
      const int kn = (kt + 1) << 6;
#pragma unroll
      for (int c = 0; c < 4; ++c) {
        async16(&As[cur ^ 1][sbase + c * 8 * 64], AgL + (size_t)c * 8 * K + kn);
        async16(&Bs[cur ^ 1][sbase + c * 8 * 64], BgL + (size_t)c * 8 * K + kn);
      }
    }
    short8 a0[4], a1[4], b0[4], b1[4];
#pragma unroll
    for (int i = 0; i < 4; ++i) {
      const ushort* p = &As[cur][(wr * 64 + i * 16 + lr) * 64];
      a0[i] = *(const short8*)(p + s0);
      a1[i] = *(const short8*)(p + (s0 ^ 32));
    }
#pragma unroll
    for (int j = 0; j < 4; ++j) {
      const ushort* p = &Bs[cur][(wc * 64 + j * 16 + lr) * 64];
      b0[j] = *(const short8*)(p + s0);
      b1[j] = *(const short8*)(p + (s0 ^ 32));
    }
#pragma unroll
    for (int i = 0; i < 4; ++i)
#pragma unroll
      for (int j = 0; j < 4; ++j) {
        acc[i][j] = __builtin_amdgcn_mfma_f32_16x16x32_bf16(
            a0[i], b0[j], acc[i][j], 0, 0, 0);
        acc[i][j] = __builtin_amdgcn_mfma_f32_16x16x32_bf16(
            a1[i], b1[j], acc[i][j], 0, 0, 0);
      }
    __syncthreads();
  }
#pragma unroll
  for (int i = 0; i < 4; ++i)
#pragma unroll
    for (int r = 0; r < 4; ++r) {
      int row = m0 + wr * 64 + i * 16 + lk * 4 + r;
#pragma unroll
      for (int j = 0; j < 4; ++j) {
        int col = n0 + wc * 64 + j * 16 + lr;
        Cp[(size_t)row * N + col] = acc[i][j][r];
      }
    }
}

// ---------------------------------------------------------------------------
// Flash attention v8: 1-wave blocks, split-K=2, XCD head mapping,
// f16 P/V, hoisted causal mask. (No V ping-pong: proven neutral, costs VGPR.)
// ---------------------------------------------------------------------------
__global__ __launch_bounds__(64) void flash_mfma(
    const ushort* __restrict__ Qg, const ushort* __restrict__ Kg,
    const ushort* __restrict__ Vg, float* __restrict__ pbuf, int T, int nqt)
{
  const int bid = blockIdx.x;
  const int xcd = bid & 7;
  const int ii = bid >> 3;
  const int h = xcd * 2 + (ii & 1);       // 2 heads per XCD
  const int sp = (ii >> 1) & 1;
  const int w  = (ii >> 2) & 3;           // q-strip within the 64-row q tile
  const int qt = (nqt - 1) - (ii >> 4);   // big q-tiles first
  const int q0 = qt * 64;
  const int nk = qt + 1;
  const int span = (nk + 1) >> 1;
  const int kb = sp * span;
  const int ke = (nk < kb + span) ? nk : (kb + span);
  const int lane = threadIdx.x & 63;
  const int lr = lane & 15, lk = lane >> 4;
  const ushort* Q = Qg + (size_t)h * T * 64;
  const ushort* K = Kg + (size_t)h * T * 64;
  const ushort* V = Vg + (size_t)h * 64 * T;   // f16 bits
  __shared__ __align__(16) ushort Ps[16 * 72];
  const float CEXP = 0.18033688f;  // 0.125 * log2(e)

  f32x4 o[4] = {};
  float ls[4] = {0.f, 0.f, 0.f, 0.f};

  if (kb < ke) {
    short8 qa0 = *(const short8*)(Q + (size_t)(q0 + w * 16 + lr) * 64 + lk * 8);
    short8 qa1 = *(const short8*)(Q + (size_t)(q0 + w * 16 + lr) * 64 + 32 + lk * 8);
    short8 kb0[4], kb1[4];
#pragma unroll
    for (int c = 0; c < 4; ++c) {
      const ushort* kp = K + (size_t)(kb * 64 + c * 16 + lr) * 64 + lk * 8;
      kb0[c] = *(const short8*)kp;
      kb1[c] = *(const short8*)(kp + 32);
    }
    for (int kt = kb; kt < ke; ++kt) {
      const int k0 = kt * 64;
      short8 vb0[4], vb1[4];
#pragma unroll
      for (int c = 0; c < 4; ++c) {
        const ushort* vp = V + (size_t)(c * 16 + lr) * T + k0 + lk * 8;
        vb0[c] = *(const short8*)vp;
        vb1[c] = *(const short8*)(vp + 32);
      }
      f32x4 s[4];
      __builtin_amdgcn_s_setprio(1);
#pragma unroll
      for (int c = 0; c < 4; ++c) {
        f32x4 z = {};
        z = __builtin_amdgcn_mfma_f32_16x16x32_bf16(qa0, kb0[c], z, 0, 0, 0);
        z = __builtin_amdgcn_mfma_f32_16x16x32_bf16(qa1, kb1[c], z, 0, 0, 0);
        s[c] = z;
      }
      __builtin_amdgcn_s_setprio(0);
      if (kt + 1 < ke) {
#pragma unroll
        for (int c = 0; c < 4; ++c) {
          const ushort* kp = K + (size_t)(k0 + 64 + c * 16 + lr) * 64 + lk * 8;
          kb0[c] = *(const short8*)kp;
          kb1[c] = *(const short8*)(kp + 32);
        }
      }
      float pv[4][4];
#pragma unroll
      for (int c = 0; c < 4; ++c)
#pragma unroll
        for (int r = 0; r < 4; ++r)
          pv[c][r] = exp2f(s[c][r] * CEXP);
      if (kt == qt) {  // uniform branch: only the diagonal tile masks
        const int rowbase = q0 + w * 16 + lk * 4;
#pragma unroll
        for (int c = 0; c < 4; ++c) {
          const int col = k0 + c * 16 + lr;
#pragma unroll
          for (int r = 0; r < 4; ++r)
            if (col > rowbase + r) pv[c][r] = 0.f;
        }
      }
#pragma unroll
      for (int c = 0; c < 4; ++c)
#pragma unroll
        for (int r = 0; r < 4; ++r) {
          ls[r] += pv[c][r];
          Ps[(lk * 4 + r) * 72 + c * 16 + lr] = f2h(pv[c][r]);
        }
      short8 pa0 = *(const short8*)(&Ps[lr * 72 + lk * 8]);
      short8 pa1 = *(const short8*)(&Ps[lr * 72 + 32 + lk * 8]);
      __builtin_amdgcn_s_setprio(1);
#pragma unroll
      for (int c = 0; c < 4; ++c) {
        o[c] = __builtin_amdgcn_mfma_f32_16x16x32_f16(
            __builtin_bit_cast(half8, pa0), __builtin_bit_cast(half8, vb0[c]),
            o[c], 0, 0, 0);
        o[c] = __builtin_amdgcn_mfma_f32_16x16x32_f16(
            __builtin_bit_cast(half8, pa1), __builtin_bit_cast(half8, vb1[c]),
            o[c], 0, 0, 0);
      }
      __builtin_amdgcn_s_setprio(0);
    }
#pragma unroll
    for (int r = 0; r < 4; ++r) {
      ls[r] += __shfl_xor(ls[r], 1);
      ls[r] += __shfl_xor(ls[r], 2);
      ls[r] += __shfl_xor(ls[r], 4);
      ls[r] += __shfl_xor(ls[r], 8);
    }
  }
  float* pb = pbuf + ((size_t)(h * nqt + qt) * NSP + sp) * 4160;
#pragma unroll
  for (int c = 0; c < 4; ++c)
#pragma unroll
    for (int r = 0; r < 4; ++r) {
      int row = w * 16 + lk * 4 + r;
      pb[(size_t)row * 64 + c * 16 + lr] = o[c][r];
    }
  if (lr == 0) {
#pragma unroll
    for (int r = 0; r < 4; ++r)
      pb[4096 + w * 16 + lk * 4 + r] = ls[r];
  }
}

// ---------------------------------------------------------------------------
// Fused flash merge + gated combine -> comb bf16 (T,E).
// Runs after rrp_scan2 / janus gemm; block b = h*nqt+qt covers 64 t rows.
// ---------------------------------------------------------------------------
__global__ __launch_bounds__(256) void merge_combine(
    const float* __restrict__ pbuf, const ushort* __restrict__ a2,
    const float* __restrict__ jraw, const float* __restrict__ denj,
    const float* __restrict__ gate, ushort* __restrict__ comb, int T, int nqt)
{
  const int b = blockIdx.x;
  const int h = b / nqt, qt = b - h * nqt;
  const float* p0 = pbuf + (size_t)b * NSP * 4160;
  const float* p1 = p0 + 4160;
  __shared__ float lsum[64];
  if (threadIdx.x < 64)
    lsum[threadIdx.x] = p0[4096 + threadIdx.x] + p1[4096 + threadIdx.x];
  float g0 = gate[h * 3 + 0], g1 = gate[h * 3 + 1], g2 = gate[h * 3 + 2];
  float mg = fmaxf(g0, fmaxf(g1, g2));
  float e0 = __expf(g0 - mg), e1 = __expf(g1 - mg), e2 = __expf(g2 - mg);
  float inv = 1.f / (e0 + e1 + e2);
  __syncthreads();
  for (int i = threadIdx.x; i < 4096; i += 256) {
    const int r = i >> 6, d = i & 63;
    const int t = qt * 64 + r;
    const float o1 = (p0[i] + p1[i]) / lsum[r];
    const size_t hd = ((size_t)h * T + t) * 64 + d;
    const float v =
        (e0 * o1 + e1 * bf2f(a2[hd]) +
         e2 * jraw[(size_t)t * EE + h * 64 + d] / denj[t]) * inv;
    comb[(size_t)t * EE + h * 64 + d] = f2bf(v);
  }
}

// ---------------------------------------------------------------------------
// Branch 2 scores v2: all 16 heads per block -> xT read ONCE total.
// grid (T/256, E/32); thread owns one t, 16 head-accumulators.
// rpart layout: (E/32 chunks, H, T).
// ---------------------------------------------------------------------------
__global__ __launch_bounds__(256) void rscore4(
    const float* __restrict__ xT, const float* __restrict__ wr,
    float* __restrict__ rpart, int T, int E)
{
  const int t = blockIdx.x * 256 + threadIdx.x;
  const int e0 = blockIdx.y * 32;
  float acc[HH] = {};
#pragma unroll 4
  for (int e = e0; e < e0 + 32; ++e) {
    const float xv = xT[(size_t)e * T + t];
    const float* wp = wr + (size_t)e * T + t;
#pragma unroll
    for (int h = 0; h < HH; ++h)
      acc[h] += xv * wp[(size_t)h * E * T];
  }
#pragma unroll
  for (int h = 0; h < HH; ++h)
    rpart[((size_t)blockIdx.y * HH + h) * T + t] = acc[h];
}

__global__ __launch_bounds__(256) void rsoftmax2(
    const float* __restrict__ rpart, float* __restrict__ w, int T)
{
  const int h = blockIdx.x;
  __shared__ float rs[TT];
  __shared__ float red[4];
  for (int t = threadIdx.x; t < T; t += 256) {
    float a = 0.f;
#pragma unroll
    for (int s = 0; s < 32; ++s) a += rpart[((size_t)s * HH + h) * T + t];
    rs[t] = a;
  }
  __syncthreads();
  float mx = -1e30f;
  for (int t = threadIdx.x; t < T; t += 256) mx = fmaxf(mx, rs[t]);
#pragma unroll
  for (int o = 32; o; o >>= 1) mx = fmaxf(mx, __shfl_xor(mx, o));
  if ((threadIdx.x & 63) == 0) red[threadIdx.x >> 6] = mx;
  __syncthreads();
  mx = fmaxf(fmaxf(red[0], red[1]), fmaxf(red[2], red[3]));
  float* wh = w + (size_t)h * T;
  for (int t = threadIdx.x; t < T; t += 256)
    wh[t] = __expf((rs[t] - mx) * 0.125f);
}

// ---------------------------------------------------------------------------
// RRP prefix scan, two passes, grid (H,32) x 1 wave.
// ---------------------------------------------------------------------------
__global__ __launch_bounds__(64) void rrp_part(
    const float* __restrict__ wgt, const ushort* __restrict__ rv,
    float* __restrict__ segsum, int T)
{
  const int h = blockIdx.x, seg = blockIdx.y, d = threadIdx.x;
  const int segLen = T >> 5;
  const float* wh = wgt + (size_t)h * T;
  const ushort* rvh = rv + (size_t)h * T * 64;
  const int kbeg = seg * segLen, kend = kbeg + segLen;
  float num = 0.f, den = 0.f;
  for (int k = kbeg; k < kend; ++k) {
    float wk = wh[k];
    num += wk * bf2f(rvh[(size_t)k * 64 + d]);
    den += wk;
  }
  float* o = segsum + ((size_t)h * 32 + seg) * 65;
  o[d] = num;
  if (d == 0) o[64] = den;
}

__global__ __launch_bounds__(64) void rrp_scan2(
    const float* __restrict__ wgt, const ushort* __restrict__ rv,
    const float* __restrict__ segsum, ushort* __restrict__ out, int T)
{
  const int h = blockIdx.x, seg = blockIdx.y, d = threadIdx.x;
  const int segLen = T >> 5;
  const float* wh = wgt + (size_t)h * T;
  const ushort* rvh = rv + (size_t)h * T * 64;
  ushort* oh = out + (size_t)h * T * 64;
  float num = 0.f, den = 0.f;
  for (int s = 0; s < seg; ++s) {
    const float* p = segsum + ((size_t)h * 32 + s) * 65;
    num += p[d];
    den += p[64];
  }
  const int kbeg = seg * segLen, kend = kbeg + segLen;
  for (int k = kbeg; k < kend; ++k) {
    float wk = wh[k];
    num += wk * bf2f(rvh[(size_t)k * 64 + d]);
    den += wk;
    oh[(size_t)k * 64 + d] = f2bf(num / den);
  }
}

// ---------------------------------------------------------------------------
// Branch 3: W[q][k] (bf16) + row denominators.
// ---------------------------------------------------------------------------
__global__ __launch_bounds__(256) void janus_w(
    const float* __restrict__ snorm, ushort* __restrict__ Wb,
    float* __restrict__ den, int T)
{
  const int q = blockIdx.x;
  const float sq = snorm[q] * 0.03125f;
  float mx = -1e30f;
  for (int k = threadIdx.x; k <= q; k += 256)
    mx = fmaxf(mx, sq * (snorm[k] * 0.03125f));
#pragma unroll
  for (int o = 32; o; o >>= 1) mx = fmaxf(mx, __shfl_xor(mx, o));
  __shared__ float red[4];
  if ((threadIdx.x & 63) == 0) red[threadIdx.x >> 6] = mx;
  __syncthreads();
  mx = fmaxf(fmaxf(red[0], red[1]), fmaxf(red[2], red[3]));
  float sum = 0.f;
  ushort* Wq = Wb + (size_t)q * T;
  for (int k = threadIdx.x; k < T; k += 256) {
    float wv = (k <= q) ? __expf(sq * (snorm[k] * 0.03125f) - mx) : 0.f;
    ushort wb = f2bf(wv);
    Wq[k] = wb;
    sum += bf2f(wb);
  }
#pragma unroll
  for (int o = 32; o; o >>= 1) sum += __shfl_xor(sum, o);
  __syncthreads();
  if ((threadIdx.x & 63) == 0) red[threadIdx.x >> 6] = sum;
  __syncthreads();
  if (threadIdx.x == 0) den[q] = red[0] + red[1] + red[2] + red[3];
}

// ---------------------------------------------------------------------------
extern "C" void kernel_launch(void* const* d_in, const int* in_sizes, int n_in,
                              void* d_out, int out_size, void* d_ws, size_t ws_size,
                              hipStream_t stream)
{
  (void)in_sizes; (void)n_in; (void)out_size; (void)ws_size;
  const float* x    = (const float*)d_in[0];
  const float* wq   = (const float*)d_in[1];
  const float* wk   = (const float*)d_in[2];
  const float* wv   = (const float*)d_in[3];
  const float* wr   = (const float*)d_in[4];
  const float* wvr  = (const float*)d_in[5];
  const float* wj   = (const float*)d_in[6];
  const float* gate = (const float*)d_in[7];
  const float* wo   = (const float*)d_in[8];
  float* out = (float*)d_out;

  const int T = TT, E = EE, H = HH;
  const int nqt = T / 64;
  const size_t TE = (size_t)T * E;
  const size_t EE2 = (size_t)E * E;
  const size_t TT2 = (size_t)T * T;

  ushort* u = (ushort*)d_ws;
  ushort* xbf   = u;
  ushort* xh    = xbf + TE;
  ushort* wqb   = xh + TE;
  ushort* wkb   = wqb + EE2;
  ushort* wvb   = wkb + EE2;
  ushort* wvrb  = wvb + EE2;
  ushort* wob   = wvrb + EE2;
  ushort* wjh   = wob + EE2;
  ushort* qhb   = wjh + EE2;      // (H,T,64) bf16
  ushort* khb   = qhb + TE;       // (H,T,64) bf16
  ushort* vtb   = khb + TE;       // (H,64,T) f16
  ushort* rvhb  = vtb + TE;       // (H,T,64) bf16
  ushort* echoT = rvhb + TE;      // (E,T)    bf16
  ushort* a2b   = echoT + TE;     // (H,T,64) bf16
  ushort* Wbf   = a2b + TE;       // (T,T)    bf16
  ushort* combb = Wbf + TT2;      // (T,E)    bf16
  float* jraw   = (float*)(combb + TE);   // (T,E) fp32
  float* wwb    = jraw + TE;              // (H,T)
  float* snorm  = wwb + (size_t)H * T;    // (T)
  float* denj   = snorm + T;              // (T)
  float* rpart  = denj + T;               // (32,H,T)
  float* segsum = rpart + (size_t)32 * H * T;   // (H,32,65)
  float* xT     = segsum + (size_t)H * 32 * 65; // (E,T) fp32
  float* pbuf   = xT + TE;                // (H,nqt,NSP,4160) fp32

  dim3 blk(256);
  // fused x conversions + transpose (writes xbf, xh, xT; zeroes snorm)
  cvt_xt<<<dim3(E / 32, T / 32), blk, 0, stream>>>(x, xbf, xh, xT, snorm);
  cvt_w_k<<<dim3((int)(EE2 / 1024), 6), blk, 0, stream>>>(
      wq, wk, wv, wvr, wo, wj, wqb, wkb, wvb, wvrb, wob, wjh, (int)EE2);

  // 4 bf16 projections + echo(f16) in one dispatch (dbuf + swizzled LDS)
  proj5<<<dim3(E / 128, T / 128, 5), blk, 0, stream>>>(
      xbf, xh, wqb, wkb, wvb, wvrb, wjh,
      qhb, khb, vtb, rvhb, echoT, snorm, T, E, E);

  // branch 2 scores: all heads per block (wr + xT each read exactly once)
  rscore4<<<dim3(T / 256, E / 32), blk, 0, stream>>>(xT, wr, rpart, T, E);
  rsoftmax2<<<H, blk, 0, stream>>>(rpart, wwb, T);

  // branch 1: flash split-K=2, 1-wave blocks (XCD-mapped 1D grid)
  flash_mfma<<<dim3(H * nqt * NSP * 4), dim3(64), 0, stream>>>(
      qhb, khb, vtb, pbuf, T, nqt);

  // branch 2: prefix scan
  rrp_part<<<dim3(H, 32), dim3(64), 0, stream>>>(wwb, rvhb, segsum, T);
  rrp_scan2<<<dim3(H, 32), dim3(64), 0, stream>>>(wwb, rvhb, segsum, a2b, T);

  // branch 3: W + causal GEMM
  janus_w<<<T, blk, 0, stream>>>(snorm, Wbf, denj, T);
  gemm_mfma<true><<<dim3(E / 128, T / 128), blk, 0, stream>>>(
      Wbf, echoT, jraw, T, E, T);

  // fused flash-merge + gated combine, then output projection
  merge_combine<<<H * nqt, blk, 0, stream>>>(pbuf, a2b, jraw, denj, gate,
                                             combb, T, nqt);
  gemm_mfma<false><<<dim3(E / 128, T / 128), blk, 0, stream>>>(
      combb, wob, (float*)out, T, E, E);
}

// Round 7
// 441.194 us; speedup vs baseline: 1.2806x; 1.2806x over previous
//
#include <hip/hip_runtime.h>
#include <cstddef>
#include <cstdint>

#define TT 2048
#define EE 1024
#define HH 16
#define NSP 2

typedef unsigned short ushort;
typedef unsigned int uint;
typedef __attribute__((ext_vector_type(8))) short short8;
typedef __attribute__((ext_vector_type(8))) _Float16 half8;
typedef __attribute__((ext_vector_type(4))) float f32x4;
typedef __attribute__((ext_vector_type(4))) ushort ushort4v;

__device__ __forceinline__ ushort f2bf(float f) {
  uint u = __builtin_bit_cast(uint, f);
  u = (u + 0x7FFFu + ((u >> 16) & 1u)) >> 16;
  return (ushort)u;
}
__device__ __forceinline__ float bf2f(ushort h) {
  return __builtin_bit_cast(float, (uint)h << 16);
}
__device__ __forceinline__ ushort f2h(float f) {
  return __builtin_bit_cast(ushort, (_Float16)f);
}

// async global->LDS, 16B per lane; lds dest = wave-uniform base + lane*16
__device__ __forceinline__ void async16(ushort* lds, const ushort* g) {
  __builtin_amdgcn_global_load_lds(
      reinterpret_cast<const __attribute__((address_space(1))) void*>(
          reinterpret_cast<uintptr_t>(g)),
      reinterpret_cast<__attribute__((address_space(3))) void*>(
          static_cast<unsigned int>(reinterpret_cast<uintptr_t>(lds))),
      16, 0, 0);
}

// ---------------------------------------------------------------------------
// Fused conversions (one dispatch, NO inter-block sync):
// z=0: x (T,E) fp32 -> xbf (bf16), xh (f16), xTbf (E,T bf16); zeroes snorm
//      in block (0,0).
// z=1..6: weight converts (wq,wk,wv,wvr,wo->bf16; wj->f16), linear blocks.
// ---------------------------------------------------------------------------
__global__ __launch_bounds__(256) void cvt_all(
    const float* __restrict__ x, ushort* __restrict__ xbf,
    ushort* __restrict__ xh, ushort* __restrict__ xTbf,
    const float* __restrict__ w0, const float* __restrict__ w1,
    const float* __restrict__ w2, const float* __restrict__ w3,
    const float* __restrict__ w4, const float* __restrict__ w5,
    ushort* __restrict__ d0, ushort* __restrict__ d1,
    ushort* __restrict__ d2, ushort* __restrict__ d3,
    ushort* __restrict__ d4, ushort* __restrict__ d5,
    float* __restrict__ snorm)
{
  const int z = blockIdx.z;
  if (z == 0) {
    __shared__ float tile[32][33];
    if (blockIdx.x == 0 && blockIdx.y == 0) {
      for (int i = threadIdx.x; i < TT; i += 256) snorm[i] = 0.f;
    }
    const int bn = blockIdx.x * 32;   // col base (E)
    const int bm = blockIdx.y * 32;   // row base (T)
    const int c4 = (threadIdx.x & 7) * 4;
    const int r  = threadIdx.x >> 3;  // 0..31
    const size_t off = (size_t)(bm + r) * EE + bn + c4;
    float4 v = *(const float4*)(x + off);
    tile[r][c4 + 0] = v.x; tile[r][c4 + 1] = v.y;
    tile[r][c4 + 2] = v.z; tile[r][c4 + 3] = v.w;
    ushort4v b, h;
    b.x = f2bf(v.x); b.y = f2bf(v.y); b.z = f2bf(v.z); b.w = f2bf(v.w);
    h.x = f2h(v.x);  h.y = f2h(v.y);  h.z = f2h(v.z);  h.w = f2h(v.w);
    *(ushort4v*)(xbf + off) = b;
    *(ushort4v*)(xh + off) = h;
    __syncthreads();
    const int t4 = (threadIdx.x & 7) * 4;   // t offset within tile
    const int e  = threadIdx.x >> 3;        // e offset within tile
    ushort4v tb;
    tb.x = f2bf(tile[t4 + 0][e]); tb.y = f2bf(tile[t4 + 1][e]);
    tb.z = f2bf(tile[t4 + 2][e]); tb.w = f2bf(tile[t4 + 3][e]);
    *(ushort4v*)(xTbf + (size_t)(bn + e) * TT + bm + t4) = tb;
    return;
  }
  const int lin = blockIdx.y * 32 + blockIdx.x;
  if (lin >= 1024) return;
  const float* src; ushort* dst;
  switch (z) {
    case 1: src = w0; dst = d0; break;
    case 2: src = w1; dst = d1; break;
    case 3: src = w2; dst = d2; break;
    case 4: src = w3; dst = d3; break;
    case 5: src = w4; dst = d4; break;
    default: src = w5; dst = d5; break;
  }
  const int i = lin * 1024 + threadIdx.x * 4;
  float4 v = *(const float4*)(src + i);
  ushort4v o;
  if (z == 6) {
    o.x = f2h(v.x); o.y = f2h(v.y); o.z = f2h(v.z); o.w = f2h(v.w);
  } else {
    o.x = f2bf(v.x); o.y = f2bf(v.y); o.z = f2bf(v.z); o.w = f2bf(v.w);
  }
  *(ushort4v*)(dst + i) = o;
}

// ---------------------------------------------------------------------------
// Merged 5-way projection GEMM (round-7 structure, unchanged):
//   BK=64, dbuf LDS, one barrier per K-step, XOR-swizzled LDS.
// z=0..3: bf16 x@W^T -> qhb/khb(OM1 bf16), vtb(OM2 f16), rvhb(OM1 bf16)
// z=4:    f16  xh@wjh^T -> echoT (E,T bf16, OM3) + snorm row norms
// ---------------------------------------------------------------------------
__global__ __launch_bounds__(256) void proj5(
    const ushort* __restrict__ Abf, const ushort* __restrict__ Ah,
    const ushort* __restrict__ B0, const ushort* __restrict__ B1,
    const ushort* __restrict__ B2, const ushort* __restrict__ B3,
    const ushort* __restrict__ B4,
    ushort* __restrict__ C0, ushort* __restrict__ C1,
    ushort* __restrict__ C2, ushort* __restrict__ C3,
    ushort* __restrict__ C4, float* __restrict__ snorm,
    int M, int N, int K)
{
  const ushort* A; const ushort* B; ushort* C; int om;
  switch (blockIdx.z) {
    case 0: A = Abf; B = B0; C = C0; om = 1; break;
    case 1: A = Abf; B = B1; C = C1; om = 1; break;
    case 2: A = Abf; B = B2; C = C2; om = 2; break;
    case 3: A = Abf; B = B3; C = C3; om = 1; break;
    default: A = Ah; B = B4; C = C4; om = 3; break;
  }
  const bool f16 = (blockIdx.z == 4);
  __shared__ __align__(16) ushort As[2][128 * 64];
  __shared__ __align__(16) ushort Bs[2][128 * 64];
  const int tid = threadIdx.x;
  const int m0 = blockIdx.y * 128, n0 = blockIdx.x * 128;
  const int w = tid >> 6, lane = tid & 63;
  const int wr = w >> 1, wc = w & 1;
  const int lr = lane & 15, lk = lane >> 4;
  const int srow = lane >> 3;                   // 0..7 within 8-row stripe
  const int scol = ((lane & 7) ^ srow) * 8;     // pre-swizzled source granule
  const ushort* AgL = A + (size_t)(m0 + w * 32 + srow) * K + scol;
  const ushort* BgL = B + (size_t)(n0 + w * 32 + srow) * K + scol;
  const int sbase = (w * 32) * 64;
  const int s0 = (lk ^ (lr & 7)) * 8;
  f32x4 acc[4][4] = {};
  const int NT = K >> 6;
#pragma unroll
  for (int c = 0; c < 4; ++c) {
    async16(&As[0][sbase + c * 8 * 64], AgL + (size_t)c * 8 * K);
    async16(&Bs[0][sbase + c * 8 * 64], BgL + (size_t)c * 8 * K);
  }
  __syncthreads();
  for (int kt = 0; kt < NT; ++kt) {
    const int cur = kt & 1;
    if (kt + 1 < NT) {
      const int kn = (kt + 1) << 6;
#pragma unroll
      for (int c = 0; c < 4; ++c) {
        async16(&As[cur ^ 1][sbase + c * 8 * 64], AgL + (size_t)c * 8 * K + kn);
        async16(&Bs[cur ^ 1][sbase + c * 8 * 64], BgL + (size_t)c * 8 * K + kn);
      }
    }
    short8 a0[4], a1[4], b0[4], b1[4];
#pragma unroll
    for (int i = 0; i < 4; ++i) {
      const ushort* p = &As[cur][(wr * 64 + i * 16 + lr) * 64];
      a0[i] = *(const short8*)(p + s0);
      a1[i] = *(const short8*)(p + (s0 ^ 32));
    }
#pragma unroll
    for (int j = 0; j < 4; ++j) {
      const ushort* p = &Bs[cur][(wc * 64 + j * 16 + lr) * 64];
      b0[j] = *(const short8*)(p + s0);
      b1[j] = *(const short8*)(p + (s0 ^ 32));
    }
    if (f16) {
#pragma unroll
      for (int i = 0; i < 4; ++i)
#pragma unroll
        for (int j = 0; j < 4; ++j) {
          acc[i][j] = __builtin_amdgcn_mfma_f32_16x16x32_f16(
              __builtin_bit_cast(half8, a0[i]), __builtin_bit_cast(half8, b0[j]),
              acc[i][j], 0, 0, 0);
          acc[i][j] = __builtin_amdgcn_mfma_f32_16x16x32_f16(
              __builtin_bit_cast(half8, a1[i]), __builtin_bit_cast(half8, b1[j]),
              acc[i][j], 0, 0, 0);
        }
    } else {
#pragma unroll
      for (int i = 0; i < 4; ++i)
#pragma unroll
        for (int j = 0; j < 4; ++j) {
          acc[i][j] = __builtin_amdgcn_mfma_f32_16x16x32_bf16(
              a0[i], b0[j], acc[i][j], 0, 0, 0);
          acc[i][j] = __builtin_amdgcn_mfma_f32_16x16x32_bf16(
              a1[i], b1[j], acc[i][j], 0, 0, 0);
        }
    }
    __syncthreads();
  }
#pragma unroll
  for (int i = 0; i < 4; ++i)
#pragma unroll
    for (int r = 0; r < 4; ++r) {
      int row = m0 + wr * 64 + i * 16 + lk * 4 + r;
#pragma unroll
      for (int j = 0; j < 4; ++j) {
        int col = n0 + wc * 64 + j * 16 + lr;
        ushort v = (om == 2) ? f2h(acc[i][j][r]) : f2bf(acc[i][j][r]);
        if (om == 1)
          C[((size_t)(col >> 6) * M + row) * 64 + (col & 63)] = v;
        else if (om == 2)
          C[(size_t)(col >> 6) * 64 * M + (size_t)(col & 63) * M + row] = v;
        else
          C[(size_t)col * M + row] = v;
      }
    }
  if (om == 3) {
#pragma unroll
    for (int i = 0; i < 4; ++i)
#pragma unroll
      for (int r = 0; r < 4; ++r) {
        float p = 0.f;
#pragma unroll
        for (int j = 0; j < 4; ++j) p += acc[i][j][r] * acc[i][j][r];
        p += __shfl_xor(p, 1); p += __shfl_xor(p, 2);
        p += __shfl_xor(p, 4); p += __shfl_xor(p, 8);
        if (lr == 0)
          atomicAdd(&snorm[m0 + wr * 64 + i * 16 + lk * 4 + r], p);
      }
  }
}

// ---------------------------------------------------------------------------
// Generic MFMA GEMM (janus / out), fp32 out (round-7 structure, unchanged).
// ---------------------------------------------------------------------------
template<bool CZ>
__global__ __launch_bounds__(256) void gemm_mfma(
    const ushort* __restrict__ A, const ushort* __restrict__ B,
    float* __restrict__ Cp, int M, int N, int K)
{
  __shared__ __align__(16) ushort As[2][128 * 64];
  __shared__ __align__(16) ushort Bs[2][128 * 64];
  const int tid = threadIdx.x;
  const int m0 = blockIdx.y * 128, n0 = blockIdx.x * 128;
  const int w = tid >> 6, lane = tid & 63;
  const int wr = w >> 1, wc = w & 1;
  const int lr = lane & 15, lk = lane >> 4;
  const int srow = lane >> 3;
  const int scol = ((lane & 7) ^ srow) * 8;
  const ushort* AgL = A + (size_t)(m0 + w * 32 + srow) * K + scol;
  const ushort* BgL = B + (size_t)(n0 + w * 32 + srow) * K + scol;
  const int sbase = (w * 32) * 64;
  const int s0 = (lk ^ (lr & 7)) * 8;
  f32x4 acc[4][4] = {};
  const int Keff = CZ ? (K < m0 + 128 ? K : m0 + 128) : K;
  const int NT = Keff >> 6;
#pragma unroll
  for (int c = 0; c < 4; ++c) {
    async16(&As[0][sbase + c * 8 * 64], AgL + (size_t)c * 8 * K);
    async16(&Bs[0][sbase + c * 8 * 64], BgL + (size_t)c * 8 * K);
  }
  __syncthreads();
  for (int kt = 0; kt < NT; ++kt) {
    const int cur = kt & 1;
    if (kt + 1 < NT) {
      const int kn = (kt + 1) << 6;
#pragma unroll
      for (int c = 0; c < 4; ++c) {
        async16(&As[cur ^ 1][sbase + c * 8 * 64], AgL + (size_t)c * 8 * K + kn);
        async16(&Bs[cur ^ 1][sbase + c * 8 * 64], BgL + (size_t)c * 8 * K + kn);
      }
    }
    short8 a0[4], a1[4], b0[4], b1[4];
#pragma unroll
    for (int i = 0; i < 4; ++i) {
      const ushort* p = &As[cur][(wr * 64 + i * 16 + lr) * 64];
      a0[i] = *(const short8*)(p + s0);
      a1[i] = *(const short8*)(p + (s0 ^ 32));
    }
#pragma unroll
    for (int j = 0; j < 4; ++j) {
      const ushort* p = &Bs[cur][(wc * 64 + j * 16 + lr) * 64];
      b0[j] = *(const short8*)(p + s0);
      b1[j] = *(const short8*)(p + (s0 ^ 32));
    }
#pragma unroll
    for (int i = 0; i < 4; ++i)
#pragma unroll
      for (int j = 0; j < 4; ++j) {
        acc[i][j] = __builtin_amdgcn_mfma_f32_16x16x32_bf16(
            a0[i], b0[j], acc[i][j], 0, 0, 0);
        acc[i][j] = __builtin_amdgcn_mfma_f32_16x16x32_bf16(
            a1[i], b1[j], acc[i][j], 0, 0, 0);
      }
    __syncthreads();
  }
#pragma unroll
  for (int i = 0; i < 4; ++i)
#pragma unroll
    for (int r = 0; r < 4; ++r) {
      int row = m0 + wr * 64 + i * 16 + lk * 4 + r;
#pragma unroll
      for (int j = 0; j < 4; ++j) {
        int col = n0 + wc * 64 + j * 16 + lr;
        Cp[(size_t)row * N + col] = acc[i][j][r];
      }
    }
}

// ---------------------------------------------------------------------------
// Flash attention v8 (unchanged): 1-wave blocks, split-K=2, XCD head map,
// f16 P/V, hoisted causal mask.
// ---------------------------------------------------------------------------
__global__ __launch_bounds__(64) void flash_mfma(
    const ushort* __restrict__ Qg, const ushort* __restrict__ Kg,
    const ushort* __restrict__ Vg, float* __restrict__ pbuf, int T, int nqt)
{
  const int bid = blockIdx.x;
  const int xcd = bid & 7;
  const int ii = bid >> 3;
  const int h = xcd * 2 + (ii & 1);       // 2 heads per XCD
  const int sp = (ii >> 1) & 1;
  const int w  = (ii >> 2) & 3;           // q-strip within the 64-row q tile
  const int qt = (nqt - 1) - (ii >> 4);   // big q-tiles first
  const int q0 = qt * 64;
  const int nk = qt + 1;
  const int span = (nk + 1) >> 1;
  const int kb = sp * span;
  const int ke = (nk < kb + span) ? nk : (kb + span);
  const int lane = threadIdx.x & 63;
  const int lr = lane & 15, lk = lane >> 4;
  const ushort* Q = Qg + (size_t)h * T * 64;
  const ushort* K = Kg + (size_t)h * T * 64;
  const ushort* V = Vg + (size_t)h * 64 * T;   // f16 bits
  __shared__ __align__(16) ushort Ps[16 * 72];
  const float CEXP = 0.18033688f;  // 0.125 * log2(e)

  f32x4 o[4] = {};
  float ls[4] = {0.f, 0.f, 0.f, 0.f};

  if (kb < ke) {
    short8 qa0 = *(const short8*)(Q + (size_t)(q0 + w * 16 + lr) * 64 + lk * 8);
    short8 qa1 = *(const short8*)(Q + (size_t)(q0 + w * 16 + lr) * 64 + 32 + lk * 8);
    short8 kb0[4], kb1[4];
#pragma unroll
    for (int c = 0; c < 4; ++c) {
      const ushort* kp = K + (size_t)(kb * 64 + c * 16 + lr) * 64 + lk * 8;
      kb0[c] = *(const short8*)kp;
      kb1[c] = *(const short8*)(kp + 32);
    }
    for (int kt = kb; kt < ke; ++kt) {
      const int k0 = kt * 64;
      short8 vb0[4], vb1[4];
#pragma unroll
      for (int c = 0; c < 4; ++c) {
        const ushort* vp = V + (size_t)(c * 16 + lr) * T + k0 + lk * 8;
        vb0[c] = *(const short8*)vp;
        vb1[c] = *(const short8*)(vp + 32);
      }
      f32x4 s[4];
      __builtin_amdgcn_s_setprio(1);
#pragma unroll
      for (int c = 0; c < 4; ++c) {
        f32x4 z = {};
        z = __builtin_amdgcn_mfma_f32_16x16x32_bf16(qa0, kb0[c], z, 0, 0, 0);
        z = __builtin_amdgcn_mfma_f32_16x16x32_bf16(qa1, kb1[c], z, 0, 0, 0);
        s[c] = z;
      }
      __builtin_amdgcn_s_setprio(0);
      if (kt + 1 < ke) {
#pragma unroll
        for (int c = 0; c < 4; ++c) {
          const ushort* kp = K + (size_t)(k0 + 64 + c * 16 + lr) * 64 + lk * 8;
          kb0[c] = *(const short8*)kp;
          kb1[c] = *(const short8*)(kp + 32);
        }
      }
      float pv[4][4];
#pragma unroll
      for (int c = 0; c < 4; ++c)
#pragma unroll
        for (int r = 0; r < 4; ++r)
          pv[c][r] = exp2f(s[c][r] * CEXP);
      if (kt == qt) {  // uniform branch: only the diagonal tile masks
        const int rowbase = q0 + w * 16 + lk * 4;
#pragma unroll
        for (int c = 0; c < 4; ++c) {
          const int col = k0 + c * 16 + lr;
#pragma unroll
          for (int r = 0; r < 4; ++r)
            if (col > rowbase + r) pv[c][r] = 0.f;
        }
      }
#pragma unroll
      for (int c = 0; c < 4; ++c)
#pragma unroll
        for (int r = 0; r < 4; ++r) {
          ls[r] += pv[c][r];
          Ps[(lk * 4 + r) * 72 + c * 16 + lr] = f2h(pv[c][r]);
        }
      short8 pa0 = *(const short8*)(&Ps[lr * 72 + lk * 8]);
      short8 pa1 = *(const short8*)(&Ps[lr * 72 + 32 + lk * 8]);
      __builtin_amdgcn_s_setprio(1);
#pragma unroll
      for (int c = 0; c < 4; ++c) {
        o[c] = __builtin_amdgcn_mfma_f32_16x16x32_f16(
            __builtin_bit_cast(half8, pa0), __builtin_bit_cast(half8, vb0[c]),
            o[c], 0, 0, 0);
        o[c] = __builtin_amdgcn_mfma_f32_16x16x32_f16(
            __builtin_bit_cast(half8, pa1), __builtin_bit_cast(half8, vb1[c]),
            o[c], 0, 0, 0);
      }
      __builtin_amdgcn_s_setprio(0);
    }
#pragma unroll
    for (int r = 0; r < 4; ++r) {
      ls[r] += __shfl_xor(ls[r], 1);
      ls[r] += __shfl_xor(ls[r], 2);
      ls[r] += __shfl_xor(ls[r], 4);
      ls[r] += __shfl_xor(ls[r], 8);
    }
  }
  float* pb = pbuf + ((size_t)(h * nqt + qt) * NSP + sp) * 4160;
#pragma unroll
  for (int c = 0; c < 4; ++c)
#pragma unroll
    for (int r = 0; r < 4; ++r) {
      int row = w * 16 + lk * 4 + r;
      pb[(size_t)row * 64 + c * 16 + lr] = o[c][r];
    }
  if (lr == 0) {
#pragma unroll
    for (int r = 0; r < 4; ++r)
      pb[4096 + w * 16 + lk * 4 + r] = ls[r];
  }
}

// ---------------------------------------------------------------------------
// Fused flash merge + gated combine -> comb bf16 (T,E). (unchanged)
// ---------------------------------------------------------------------------
__global__ __launch_bounds__(256) void merge_combine(
    const float* __restrict__ pbuf, const ushort* __restrict__ a2,
    const float* __restrict__ jraw, const float* __restrict__ denj,
    const float* __restrict__ gate, ushort* __restrict__ comb, int T, int nqt)
{
  const int b = blockIdx.x;
  const int h = b / nqt, qt = b - h * nqt;
  const float* p0 = pbuf + (size_t)b * NSP * 4160;
  const float* p1 = p0 + 4160;
  __shared__ float lsum[64];
  if (threadIdx.x < 64)
    lsum[threadIdx.x] = p0[4096 + threadIdx.x] + p1[4096 + threadIdx.x];
  float g0 = gate[h * 3 + 0], g1 = gate[h * 3 + 1], g2 = gate[h * 3 + 2];
  float mg = fmaxf(g0, fmaxf(g1, g2));
  float e0 = __expf(g0 - mg), e1 = __expf(g1 - mg), e2 = __expf(g2 - mg);
  float inv = 1.f / (e0 + e1 + e2);
  __syncthreads();
  for (int i = threadIdx.x; i < 4096; i += 256) {
    const int r = i >> 6, d = i & 63;
    const int t = qt * 64 + r;
    const float o1 = (p0[i] + p1[i]) / lsum[r];
    const size_t hd = ((size_t)h * T + t) * 64 + d;
    const float v =
        (e0 * o1 + e1 * bf2f(a2[hd]) +
         e2 * jraw[(size_t)t * EE + h * 64 + d] / denj[t]) * inv;
    comb[(size_t)t * EE + h * 64 + d] = f2bf(v);
  }
}

// ---------------------------------------------------------------------------
// Branch 2 scores: proven rscore3 structure (float4 wr, 512 blocks) with
// bf16 xT stream. rpart: (16 e-chunks, H, T). No inter-block sync.
// ---------------------------------------------------------------------------
__global__ __launch_bounds__(256) void rscore6(
    const ushort* __restrict__ xTbf, const float* __restrict__ wr,
    float* __restrict__ rpart, int T, int E)
{
  const int h = blockIdx.y;
  const int e0 = blockIdx.z * 64;
  const int t0 = (blockIdx.x * 256 + threadIdx.x) * 4;
  const float* wrh = wr + (size_t)h * E * T;
  float4 acc = {0.f, 0.f, 0.f, 0.f};
#pragma unroll 4
  for (int e = e0; e < e0 + 64; ++e) {
    ushort4v xv = *(const ushort4v*)(xTbf + (size_t)e * T + t0);
    float4 wv = *(const float4*)(wrh + (size_t)e * T + t0);
    acc.x += bf2f(xv.x) * wv.x;
    acc.y += bf2f(xv.y) * wv.y;
    acc.z += bf2f(xv.z) * wv.z;
    acc.w += bf2f(xv.w) * wv.w;
  }
  *(float4*)(rpart + ((size_t)blockIdx.z * HH + h) * T + t0) = acc;
}

__global__ __launch_bounds__(256) void rsoftmax2(
    const float* __restrict__ rpart, float* __restrict__ w, int T)
{
  const int h = blockIdx.x;
  __shared__ float rs[TT];
  __shared__ float red[4];
  for (int t = threadIdx.x; t < T; t += 256) {
    float a = 0.f;
#pragma unroll
    for (int s = 0; s < 16; ++s) a += rpart[((size_t)s * HH + h) * T + t];
    rs[t] = a;
  }
  __syncthreads();
  float mx = -1e30f;
  for (int t = threadIdx.x; t < T; t += 256) mx = fmaxf(mx, rs[t]);
#pragma unroll
  for (int o = 32; o; o >>= 1) mx = fmaxf(mx, __shfl_xor(mx, o));
  if ((threadIdx.x & 63) == 0) red[threadIdx.x >> 6] = mx;
  __syncthreads();
  mx = fmaxf(fmaxf(red[0], red[1]), fmaxf(red[2], red[3]));
  float* wh = w + (size_t)h * T;
  for (int t = threadIdx.x; t < T; t += 256)
    wh[t] = __expf((rs[t] - mx) * 0.125f);
}

// ---------------------------------------------------------------------------
// RRP prefix scan, two passes (proven, barrier-free), grid (H,32) x 1 wave.
// ---------------------------------------------------------------------------
__global__ __launch_bounds__(64) void rrp_part(
    const float* __restrict__ wgt, const ushort* __restrict__ rv,
    float* __restrict__ segsum, int T)
{
  const int h = blockIdx.x, seg = blockIdx.y, d = threadIdx.x;
  const int segLen = T >> 5;
  const float* wh = wgt + (size_t)h * T;
  const ushort* rvh = rv + (size_t)h * T * 64;
  const int kbeg = seg * segLen, kend = kbeg + segLen;
  float num = 0.f, den = 0.f;
  for (int k = kbeg; k < kend; ++k) {
    float wk = wh[k];
    num += wk * bf2f(rvh[(size_t)k * 64 + d]);
    den += wk;
  }
  float* o = segsum + ((size_t)h * 32 + seg) * 65;
  o[d] = num;
  if (d == 0) o[64] = den;
}

__global__ __launch_bounds__(64) void rrp_scan2(
    const float* __restrict__ wgt, const ushort* __restrict__ rv,
    const float* __restrict__ segsum, ushort* __restrict__ out, int T)
{
  const int h = blockIdx.x, seg = blockIdx.y, d = threadIdx.x;
  const int segLen = T >> 5;
  const float* wh = wgt + (size_t)h * T;
  const ushort* rvh = rv + (size_t)h * T * 64;
  ushort* oh = out + (size_t)h * T * 64;
  float num = 0.f, den = 0.f;
  for (int s = 0; s < seg; ++s) {
    const float* p = segsum + ((size_t)h * 32 + s) * 65;
    num += p[d];
    den += p[64];
  }
  const int kbeg = seg * segLen, kend = kbeg + segLen;
  for (int k = kbeg; k < kend; ++k) {
    float wk = wh[k];
    num += wk * bf2f(rvh[(size_t)k * 64 + d]);
    den += wk;
    oh[(size_t)k * 64 + d] = f2bf(num / den);
  }
}

// ---------------------------------------------------------------------------
// Branch 3: W[q][k] (bf16) + row denominators. (unchanged)
// ---------------------------------------------------------------------------
__global__ __launch_bounds__(256) void janus_w(
    const float* __restrict__ snorm, ushort* __restrict__ Wb,
    float* __restrict__ den, int T)
{
  const int q = blockIdx.x;
  const float sq = snorm[q] * 0.03125f;
  float mx = -1e30f;
  for (int k = threadIdx.x; k <= q; k += 256)
    mx = fmaxf(mx, sq * (snorm[k] * 0.03125f));
#pragma unroll
  for (int o = 32; o; o >>= 1) mx = fmaxf(mx, __shfl_xor(mx, o));
  __shared__ float red[4];
  if ((threadIdx.x & 63) == 0) red[threadIdx.x >> 6] = mx;
  __syncthreads();
  mx = fmaxf(fmaxf(red[0], red[1]), fmaxf(red[2], red[3]));
  float sum = 0.f;
  ushort* Wq = Wb + (size_t)q * T;
  for (int k = threadIdx.x; k < T; k += 256) {
    float wv = (k <= q) ? __expf(sq * (snorm[k] * 0.03125f) - mx) : 0.f;
    ushort wb = f2bf(wv);
    Wq[k] = wb;
    sum += bf2f(wb);
  }
#pragma unroll
  for (int o = 32; o; o >>= 1) sum += __shfl_xor(sum, o);
  __syncthreads();
  if ((threadIdx.x & 63) == 0) red[threadIdx.x >> 6] = sum;
  __syncthreads();
  if (threadIdx.x == 0) den[q] = red[0] + red[1] + red[2] + red[3];
}

// ---------------------------------------------------------------------------
extern "C" void kernel_launch(void* const* d_in, const int* in_sizes, int n_in,
                              void* d_out, int out_size, void* d_ws, size_t ws_size,
                              hipStream_t stream)
{
  (void)in_sizes; (void)n_in; (void)out_size; (void)ws_size;
  const float* x    = (const float*)d_in[0];
  const float* wq   = (const float*)d_in[1];
  const float* wk   = (const float*)d_in[2];
  const float* wv   = (const float*)d_in[3];
  const float* wr   = (const float*)d_in[4];
  const float* wvr  = (const float*)d_in[5];
  const float* wj   = (const float*)d_in[6];
  const float* gate = (const float*)d_in[7];
  const float* wo   = (const float*)d_in[8];
  float* out = (float*)d_out;

  const int T = TT, E = EE, H = HH;
  const int nqt = T / 64;
  const size_t TE = (size_t)T * E;
  const size_t EE2 = (size_t)E * E;
  const size_t TT2 = (size_t)T * T;

  ushort* u = (ushort*)d_ws;
  ushort* xbf   = u;
  ushort* xh    = xbf + TE;
  ushort* xTbf  = xh + TE;        // (E,T) bf16
  ushort* wqb   = xTbf + TE;
  ushort* wkb   = wqb + EE2;
  ushort* wvb   = wkb + EE2;
  ushort* wvrb  = wvb + EE2;
  ushort* wob   = wvrb + EE2;
  ushort* wjh   = wob + EE2;
  ushort* qhb   = wjh + EE2;      // (H,T,64) bf16
  ushort* khb   = qhb + TE;       // (H,T,64) bf16
  ushort* vtb   = khb + TE;       // (H,64,T) f16
  ushort* rvhb  = vtb + TE;       // (H,T,64) bf16
  ushort* echoT = rvhb + TE;      // (E,T)    bf16
  ushort* a2b   = echoT + TE;     // (H,T,64) bf16
  ushort* Wbf   = a2b + TE;       // (T,T)    bf16
  ushort* combb = Wbf + TT2;      // (T,E)    bf16
  float* jraw   = (float*)(combb + TE);   // (T,E) fp32
  float* wwb    = jraw + TE;              // (H,T)
  float* snorm  = wwb + (size_t)H * T;    // (T)
  float* denj   = snorm + T;              // (T)
  float* rpart  = denj + T;               // (16,H,T)
  float* segsum = rpart + (size_t)16 * H * T;   // (H,32,65)
  float* pbuf   = segsum + (size_t)H * 32 * 65; // (H,nqt,NSP,4160) fp32

  dim3 blk(256);
  // all input conversions in ONE dispatch (also zeroes snorm)
  cvt_all<<<dim3(E / 32, T / 32, 7), blk, 0, stream>>>(
      x, xbf, xh, xTbf, wq, wk, wv, wvr, wo, wj,
      wqb, wkb, wvb, wvrb, wob, wjh, snorm);

  // 4 bf16 projections + echo(f16) in one dispatch (dbuf + swizzled LDS)
  proj5<<<dim3(E / 128, T / 128, 5), blk, 0, stream>>>(
      xbf, xh, wqb, wkb, wvb, wvrb, wjh,
      qhb, khb, vtb, rvhb, echoT, snorm, T, E, E);

  // branch 2 scores (bf16 xT + f32 wr) + softmax
  rscore6<<<dim3(T / 1024, H, E / 64), blk, 0, stream>>>(
      xTbf, wr, rpart, T, E);
  rsoftmax2<<<H, blk, 0, stream>>>(rpart, wwb, T);

  // branch 1: flash split-K=2, 1-wave blocks (XCD-mapped 1D grid)
  flash_mfma<<<dim3(H * nqt * NSP * 4), dim3(64), 0, stream>>>(
      qhb, khb, vtb, pbuf, T, nqt);

  // branch 2: prefix scan (proven 2-pass)
  rrp_part<<<dim3(H, 32), dim3(64), 0, stream>>>(wwb, rvhb, segsum, T);
  rrp_scan2<<<dim3(H, 32), dim3(64), 0, stream>>>(wwb, rvhb, segsum, a2b, T);

  // branch 3: W + causal GEMM
  janus_w<<<T, blk, 0, stream>>>(snorm, Wbf, denj, T);
  gemm_mfma<true><<<dim3(E / 128, T / 128), blk, 0, stream>>>(
      Wbf, echoT, jraw, T, E, T);

  // fused flash-merge + gated combine, then output projection
  merge_combine<<<H * nqt, blk, 0, stream>>>(pbuf, a2b, jraw, denj, gate,
                                             combb, T, nqt);
  gemm_mfma<false><<<dim3(E / 128, T / 128), blk, 0, stream>>>(
      combb, wob, (float*)out, T, E, E);
}

// Round 8
// 416.245 us; speedup vs baseline: 1.3573x; 1.0599x over previous
//
#include <hip/hip_runtime.h>
#include <cstddef>
#include <cstdint>

#define TT 2048
#define EE 1024
#define HH 16

typedef unsigned short ushort;
typedef unsigned int uint;
typedef __attribute__((ext_vector_type(8))) short short8;
typedef __attribute__((ext_vector_type(8))) _Float16 half8;
typedef __attribute__((ext_vector_type(4))) float f32x4;
typedef __attribute__((ext_vector_type(4))) ushort ushort4v;

__device__ __forceinline__ ushort f2bf(float f) {
  uint u = __builtin_bit_cast(uint, f);
  u = (u + 0x7FFFu + ((u >> 16) & 1u)) >> 16;
  return (ushort)u;
}
__device__ __forceinline__ float bf2f(ushort h) {
  return __builtin_bit_cast(float, (uint)h << 16);
}
__device__ __forceinline__ ushort f2h(float f) {
  return __builtin_bit_cast(ushort, (_Float16)f);
}

// async global->LDS, 16B per lane; lds dest = wave-uniform base + lane*16
__device__ __forceinline__ void async16(ushort* lds, const ushort* g) {
  __builtin_amdgcn_global_load_lds(
      reinterpret_cast<const __attribute__((address_space(1))) void*>(
          reinterpret_cast<uintptr_t>(g)),
      reinterpret_cast<__attribute__((address_space(3))) void*>(
          static_cast<unsigned int>(reinterpret_cast<uintptr_t>(lds))),
      16, 0, 0);
}

// ---------------------------------------------------------------------------
// Fused conversions (one dispatch, NO inter-block sync):
// z=0: x (T,E) fp32 -> xbf (bf16), xh (f16), xTbf (E,T bf16); zeroes snorm
//      in block (0,0).
// z=1..6: weight converts (wq,wk,wv,wvr,wo->bf16; wj->f16), linear blocks.
// ---------------------------------------------------------------------------
__global__ __launch_bounds__(256) void cvt_all(
    const float* __restrict__ x, ushort* __restrict__ xbf,
    ushort* __restrict__ xh, ushort* __restrict__ xTbf,
    const float* __restrict__ w0, const float* __restrict__ w1,
    const float* __restrict__ w2, const float* __restrict__ w3,
    const float* __restrict__ w4, const float* __restrict__ w5,
    ushort* __restrict__ d0, ushort* __restrict__ d1,
    ushort* __restrict__ d2, ushort* __restrict__ d3,
    ushort* __restrict__ d4, ushort* __restrict__ d5,
    float* __restrict__ snorm)
{
  const int z = blockIdx.z;
  if (z == 0) {
    __shared__ float tile[32][33];
    if (blockIdx.x == 0 && blockIdx.y == 0) {
      for (int i = threadIdx.x; i < TT; i += 256) snorm[i] = 0.f;
    }
    const int bn = blockIdx.x * 32;   // col base (E)
    const int bm = blockIdx.y * 32;   // row base (T)
    const int c4 = (threadIdx.x & 7) * 4;
    const int r  = threadIdx.x >> 3;  // 0..31
    const size_t off = (size_t)(bm + r) * EE + bn + c4;
    float4 v = *(const float4*)(x + off);
    tile[r][c4 + 0] = v.x; tile[r][c4 + 1] = v.y;
    tile[r][c4 + 2] = v.z; tile[r][c4 + 3] = v.w;
    ushort4v b, h;
    b.x = f2bf(v.x); b.y = f2bf(v.y); b.z = f2bf(v.z); b.w = f2bf(v.w);
    h.x = f2h(v.x);  h.y = f2h(v.y);  h.z = f2h(v.z);  h.w = f2h(v.w);
    *(ushort4v*)(xbf + off) = b;
    *(ushort4v*)(xh + off) = h;
    __syncthreads();
    const int t4 = (threadIdx.x & 7) * 4;   // t offset within tile
    const int e  = threadIdx.x >> 3;        // e offset within tile
    ushort4v tb;
    tb.x = f2bf(tile[t4 + 0][e]); tb.y = f2bf(tile[t4 + 1][e]);
    tb.z = f2bf(tile[t4 + 2][e]); tb.w = f2bf(tile[t4 + 3][e]);
    *(ushort4v*)(xTbf + (size_t)(bn + e) * TT + bm + t4) = tb;
    return;
  }
  const int lin = blockIdx.y * 32 + blockIdx.x;
  if (lin >= 1024) return;
  const float* src; ushort* dst;
  switch (z) {
    case 1: src = w0; dst = d0; break;
    case 2: src = w1; dst = d1; break;
    case 3: src = w2; dst = d2; break;
    case 4: src = w3; dst = d3; break;
    case 5: src = w4; dst = d4; break;
    default: src = w5; dst = d5; break;
  }
  const int i = lin * 1024 + threadIdx.x * 4;
  float4 v = *(const float4*)(src + i);
  ushort4v o;
  if (z == 6) {
    o.x = f2h(v.x); o.y = f2h(v.y); o.z = f2h(v.z); o.w = f2h(v.w);
  } else {
    o.x = f2bf(v.x); o.y = f2bf(v.y); o.z = f2bf(v.z); o.w = f2bf(v.w);
  }
  *(ushort4v*)(dst + i) = o;
}

// ---------------------------------------------------------------------------
// Merged 5-way projection GEMM (round-7 structure, unchanged):
//   BK=64, dbuf LDS, one barrier per K-step, XOR-swizzled LDS.
// z=0..3: bf16 x@W^T -> qhb/khb(OM1 bf16), vtb(OM2 f16), rvhb(OM1 bf16)
// z=4:    f16  xh@wjh^T -> echoT (E,T bf16, OM3) + snorm row norms
// ---------------------------------------------------------------------------
__global__ __launch_bounds__(256) void proj5(
    const ushort* __restrict__ Abf, const ushort* __restrict__ Ah,
    const ushort* __restrict__ B0, const ushort* __restrict__ B1,
    const ushort* __restrict__ B2, const ushort* __restrict__ B3,
    const ushort* __restrict__ B4,
    ushort* __restrict__ C0, ushort* __restrict__ C1,
    ushort* __restrict__ C2, ushort* __restrict__ C3,
    ushort* __restrict__ C4, float* __restrict__ snorm,
    int M, int N, int K)
{
  const ushort* A; const ushort* B; ushort* C; int om;
  switch (blockIdx.z) {
    case 0: A = Abf; B = B0; C = C0; om = 1; break;
    case 1: A = Abf; B = B1; C = C1; om = 1; break;
    case 2: A = Abf; B = B2; C = C2; om = 2; break;
    case 3: A = Abf; B = B3; C = C3; om = 1; break;
    default: A = Ah; B = B4; C = C4; om = 3; break;
  }
  const bool f16 = (blockIdx.z == 4);
  __shared__ __align__(16) ushort As[2][128 * 64];
  __shared__ __align__(16) ushort Bs[2][128 * 64];
  const int tid = threadIdx.x;
  const int m0 = blockIdx.y * 128, n0 = blockIdx.x * 128;
  const int w = tid >> 6, lane = tid & 63;
  const int wr = w >> 1, wc = w & 1;
  const int lr = lane & 15, lk = lane >> 4;
  const int srow = lane >> 3;                   // 0..7 within 8-row stripe
  const int scol = ((lane & 7) ^ srow) * 8;     // pre-swizzled source granule
  const ushort* AgL = A + (size_t)(m0 + w * 32 + srow) * K + scol;
  const ushort* BgL = B + (size_t)(n0 + w * 32 + srow) * K + scol;
  const int sbase = (w * 32) * 64;
  const int s0 = (lk ^ (lr & 7)) * 8;
  f32x4 acc[4][4] = {};
  const int NT = K >> 6;
#pragma unroll
  for (int c = 0; c < 4; ++c) {
    async16(&As[0][sbase + c * 8 * 64], AgL + (size_t)c * 8 * K);
    async16(&Bs[0][sbase + c * 8 * 64], BgL + (size_t)c * 8 * K);
  }
  __syncthreads();
  for (int kt = 0; kt < NT; ++kt) {
    const int cur = kt & 1;
    if (kt + 1 < NT) {
      const int kn = (kt + 1) << 6;
#pragma unroll
      for (int c = 0; c < 4; ++c) {
        async16(&As[cur ^ 1][sbase + c * 8 * 64], AgL + (size_t)c * 8 * K + kn);
        async16(&Bs[cur ^ 1][sbase + c * 8 * 64], BgL + (size_t)c * 8 * K + kn);
      }
    }
    short8 a0[4], a1[4], b0[4], b1[4];
#pragma unroll
    for (int i = 0; i < 4; ++i) {
      const ushort* p = &As[cur][(wr * 64 + i * 16 + lr) * 64];
      a0[i] = *(const short8*)(p + s0);
      a1[i] = *(const short8*)(p + (s0 ^ 32));
    }
#pragma unroll
    for (int j = 0; j < 4; ++j) {
      const ushort* p = &Bs[cur][(wc * 64 + j * 16 + lr) * 64];
      b0[j] = *(const short8*)(p + s0);
      b1[j] = *(const short8*)(p + (s0 ^ 32));
    }
    if (f16) {
#pragma unroll
      for (int i = 0; i < 4; ++i)
#pragma unroll
        for (int j = 0; j < 4; ++j) {
          acc[i][j] = __builtin_amdgcn_mfma_f32_16x16x32_f16(
              __builtin_bit_cast(half8, a0[i]), __builtin_bit_cast(half8, b0[j]),
              acc[i][j], 0, 0, 0);
          acc[i][j] = __builtin_amdgcn_mfma_f32_16x16x32_f16(
              __builtin_bit_cast(half8, a1[i]), __builtin_bit_cast(half8, b1[j]),
              acc[i][j], 0, 0, 0);
        }
    } else {
#pragma unroll
      for (int i = 0; i < 4; ++i)
#pragma unroll
        for (int j = 0; j < 4; ++j) {
          acc[i][j] = __builtin_amdgcn_mfma_f32_16x16x32_bf16(
              a0[i], b0[j], acc[i][j], 0, 0, 0);
          acc[i][j] = __builtin_amdgcn_mfma_f32_16x16x32_bf16(
              a1[i], b1[j], acc[i][j], 0, 0, 0);
        }
    }
    __syncthreads();
  }
#pragma unroll
  for (int i = 0; i < 4; ++i)
#pragma unroll
    for (int r = 0; r < 4; ++r) {
      int row = m0 + wr * 64 + i * 16 + lk * 4 + r;
#pragma unroll
      for (int j = 0; j < 4; ++j) {
        int col = n0 + wc * 64 + j * 16 + lr;
        ushort v = (om == 2) ? f2h(acc[i][j][r]) : f2bf(acc[i][j][r]);
        if (om == 1)
          C[((size_t)(col >> 6) * M + row) * 64 + (col & 63)] = v;
        else if (om == 2)
          C[(size_t)(col >> 6) * 64 * M + (size_t)(col & 63) * M + row] = v;
        else
          C[(size_t)col * M + row] = v;
      }
    }
  if (om == 3) {
#pragma unroll
    for (int i = 0; i < 4; ++i)
#pragma unroll
      for (int r = 0; r < 4; ++r) {
        float p = 0.f;
#pragma unroll
        for (int j = 0; j < 4; ++j) p += acc[i][j][r] * acc[i][j][r];
        p += __shfl_xor(p, 1); p += __shfl_xor(p, 2);
        p += __shfl_xor(p, 4); p += __shfl_xor(p, 8);
        if (lr == 0)
          atomicAdd(&snorm[m0 + wr * 64 + i * 16 + lk * 4 + r], p);
      }
  }
}

// ---------------------------------------------------------------------------
// Generic MFMA GEMM (janus / out), fp32 out (round-7 structure, unchanged).
// ---------------------------------------------------------------------------
template<bool CZ>
__global__ __launch_bounds__(256) void gemm_mfma(
    const ushort* __restrict__ A, const ushort* __restrict__ B,
    float* __restrict__ Cp, int M, int N, int K)
{
  __shared__ __align__(16) ushort As[2][128 * 64];
  __shared__ __align__(16) ushort Bs[2][128 * 64];
  const int tid = threadIdx.x;
  const int m0 = blockIdx.y * 128, n0 = blockIdx.x * 128;
  const int w = tid >> 6, lane = tid & 63;
  const int wr = w >> 1, wc = w & 1;
  const int lr = lane & 15, lk = lane >> 4;
  const int srow = lane >> 3;
  const int scol = ((lane & 7) ^ srow) * 8;
  const ushort* AgL = A + (size_t)(m0 + w * 32 + srow) * K + scol;
  const ushort* BgL = B + (size_t)(n0 + w * 32 + srow) * K + scol;
  const int sbase = (w * 32) * 64;
  const int s0 = (lk ^ (lr & 7)) * 8;
  f32x4 acc[4][4] = {};
  const int Keff = CZ ? (K < m0 + 128 ? K : m0 + 128) : K;
  const int NT = Keff >> 6;
#pragma unroll
  for (int c = 0; c < 4; ++c) {
    async16(&As[0][sbase + c * 8 * 64], AgL + (size_t)c * 8 * K);
    async16(&Bs[0][sbase + c * 8 * 64], BgL + (size_t)c * 8 * K);
  }
  __syncthreads();
  for (int kt = 0; kt < NT; ++kt) {
    const int cur = kt & 1;
    if (kt + 1 < NT) {
      const int kn = (kt + 1) << 6;
#pragma unroll
      for (int c = 0; c < 4; ++c) {
        async16(&As[cur ^ 1][sbase + c * 8 * 64], AgL + (size_t)c * 8 * K + kn);
        async16(&Bs[cur ^ 1][sbase + c * 8 * 64], BgL + (size_t)c * 8 * K + kn);
      }
    }
    short8 a0[4], a1[4], b0[4], b1[4];
#pragma unroll
    for (int i = 0; i < 4; ++i) {
      const ushort* p = &As[cur][(wr * 64 + i * 16 + lr) * 64];
      a0[i] = *(const short8*)(p + s0);
      a1[i] = *(const short8*)(p + (s0 ^ 32));
    }
#pragma unroll
    for (int j = 0; j < 4; ++j) {
      const ushort* p = &Bs[cur][(wc * 64 + j * 16 + lr) * 64];
      b0[j] = *(const short8*)(p + s0);
      b1[j] = *(const short8*)(p + (s0 ^ 32));
    }
#pragma unroll
    for (int i = 0; i < 4; ++i)
#pragma unroll
      for (int j = 0; j < 4; ++j) {
        acc[i][j] = __builtin_amdgcn_mfma_f32_16x16x32_bf16(
            a0[i], b0[j], acc[i][j], 0, 0, 0);
        acc[i][j] = __builtin_amdgcn_mfma_f32_16x16x32_bf16(
            a1[i], b1[j], acc[i][j], 0, 0, 0);
      }
    __syncthreads();
  }
#pragma unroll
  for (int i = 0; i < 4; ++i)
#pragma unroll
    for (int r = 0; r < 4; ++r) {
      int row = m0 + wr * 64 + i * 16 + lk * 4 + r;
#pragma unroll
      for (int j = 0; j < 4; ++j) {
        int col = n0 + wc * 64 + j * 16 + lr;
        Cp[(size_t)row * N + col] = acc[i][j][r];
      }
    }
}

// ---------------------------------------------------------------------------
// Flash attention v9: NSP=1 (no split) + in-kernel normalization.
// Each 1-wave block owns one (h, qt, q-strip) and the full k range, so it
// holds the complete row sums -> divides and writes bf16 a1 directly.
// No pbuf, no merge pass. XCD head mapping; qt-descending (longest first).
// ---------------------------------------------------------------------------
__global__ __launch_bounds__(64) void flash_mfma(
    const ushort* __restrict__ Qg, const ushort* __restrict__ Kg,
    const ushort* __restrict__ Vg, ushort* __restrict__ O, int T, int nqt)
{
  const int bid = blockIdx.x;
  const int xcd = bid & 7;
  const int ii = bid >> 3;
  const int h = xcd * 2 + (ii & 1);       // 2 heads per XCD
  const int w  = (ii >> 1) & 3;           // q-strip within the 64-row q tile
  const int qt = (nqt - 1) - (ii >> 3);   // big q-tiles dispatched first
  const int q0 = qt * 64;
  const int ke = qt + 1;
  const int lane = threadIdx.x & 63;
  const int lr = lane & 15, lk = lane >> 4;
  const ushort* Q = Qg + (size_t)h * T * 64;
  const ushort* K = Kg + (size_t)h * T * 64;
  const ushort* V = Vg + (size_t)h * 64 * T;   // f16 bits
  __shared__ __align__(16) ushort Ps[16 * 72];
  const float CEXP = 0.18033688f;  // 0.125 * log2(e)

  f32x4 o[4] = {};
  float ls[4] = {0.f, 0.f, 0.f, 0.f};

  short8 qa0 = *(const short8*)(Q + (size_t)(q0 + w * 16 + lr) * 64 + lk * 8);
  short8 qa1 = *(const short8*)(Q + (size_t)(q0 + w * 16 + lr) * 64 + 32 + lk * 8);
  short8 kb0[4], kb1[4];
#pragma unroll
  for (int c = 0; c < 4; ++c) {
    const ushort* kp = K + (size_t)(c * 16 + lr) * 64 + lk * 8;
    kb0[c] = *(const short8*)kp;
    kb1[c] = *(const short8*)(kp + 32);
  }
  for (int kt = 0; kt < ke; ++kt) {
    const int k0 = kt * 64;
    short8 vb0[4], vb1[4];
#pragma unroll
    for (int c = 0; c < 4; ++c) {
      const ushort* vp = V + (size_t)(c * 16 + lr) * T + k0 + lk * 8;
      vb0[c] = *(const short8*)vp;
      vb1[c] = *(const short8*)(vp + 32);
    }
    f32x4 s[4];
    __builtin_amdgcn_s_setprio(1);
#pragma unroll
    for (int c = 0; c < 4; ++c) {
      f32x4 z = {};
      z = __builtin_amdgcn_mfma_f32_16x16x32_bf16(qa0, kb0[c], z, 0, 0, 0);
      z = __builtin_amdgcn_mfma_f32_16x16x32_bf16(qa1, kb1[c], z, 0, 0, 0);
      s[c] = z;
    }
    __builtin_amdgcn_s_setprio(0);
    if (kt + 1 < ke) {
#pragma unroll
      for (int c = 0; c < 4; ++c) {
        const ushort* kp = K + (size_t)(k0 + 64 + c * 16 + lr) * 64 + lk * 8;
        kb0[c] = *(const short8*)kp;
        kb1[c] = *(const short8*)(kp + 32);
      }
    }
    float pv[4][4];
#pragma unroll
    for (int c = 0; c < 4; ++c)
#pragma unroll
      for (int r = 0; r < 4; ++r)
        pv[c][r] = exp2f(s[c][r] * CEXP);
    if (kt == qt) {  // uniform branch: only the diagonal tile masks
      const int rowbase = q0 + w * 16 + lk * 4;
#pragma unroll
      for (int c = 0; c < 4; ++c) {
        const int col = k0 + c * 16 + lr;
#pragma unroll
        for (int r = 0; r < 4; ++r)
          if (col > rowbase + r) pv[c][r] = 0.f;
      }
    }
#pragma unroll
    for (int c = 0; c < 4; ++c)
#pragma unroll
      for (int r = 0; r < 4; ++r) {
        ls[r] += pv[c][r];
        Ps[(lk * 4 + r) * 72 + c * 16 + lr] = f2h(pv[c][r]);
      }
    short8 pa0 = *(const short8*)(&Ps[lr * 72 + lk * 8]);
    short8 pa1 = *(const short8*)(&Ps[lr * 72 + 32 + lk * 8]);
    __builtin_amdgcn_s_setprio(1);
#pragma unroll
    for (int c = 0; c < 4; ++c) {
      o[c] = __builtin_amdgcn_mfma_f32_16x16x32_f16(
          __builtin_bit_cast(half8, pa0), __builtin_bit_cast(half8, vb0[c]),
          o[c], 0, 0, 0);
      o[c] = __builtin_amdgcn_mfma_f32_16x16x32_f16(
          __builtin_bit_cast(half8, pa1), __builtin_bit_cast(half8, vb1[c]),
          o[c], 0, 0, 0);
    }
    __builtin_amdgcn_s_setprio(0);
  }
#pragma unroll
  for (int r = 0; r < 4; ++r) {
    ls[r] += __shfl_xor(ls[r], 1);
    ls[r] += __shfl_xor(ls[r], 2);
    ls[r] += __shfl_xor(ls[r], 4);
    ls[r] += __shfl_xor(ls[r], 8);
    ls[r] = 1.f / ls[r];
  }
  ushort* Oh = O + ((size_t)h * T + q0) * 64;
#pragma unroll
  for (int c = 0; c < 4; ++c)
#pragma unroll
    for (int r = 0; r < 4; ++r) {
      int row = w * 16 + lk * 4 + r;
      Oh[(size_t)row * 64 + c * 16 + lr] = f2bf(o[c][r] * ls[r]);
    }
}

// ---------------------------------------------------------------------------
// Gated combine -> comb bf16 (T,E). (proven round-0..4 form)
// ---------------------------------------------------------------------------
__global__ __launch_bounds__(256) void combine_kernel(
    const ushort* __restrict__ a1, const ushort* __restrict__ a2,
    const float* __restrict__ jraw, const float* __restrict__ denj,
    const float* __restrict__ gate, ushort* __restrict__ comb, int T)
{
  const int idx = blockIdx.x * 256 + threadIdx.x;
  const int t = idx >> 10;
  const int c = idx & 1023;
  const int h = c >> 6;
  const int d = c & 63;
  float g0 = gate[h * 3 + 0], g1 = gate[h * 3 + 1], g2 = gate[h * 3 + 2];
  float mg = fmaxf(g0, fmaxf(g1, g2));
  float e0 = __expf(g0 - mg), e1 = __expf(g1 - mg), e2 = __expf(g2 - mg);
  float inv = 1.f / (e0 + e1 + e2);
  const size_t hd = ((size_t)h * T + t) * 64 + d;
  float v = (e0 * bf2f(a1[hd]) + e1 * bf2f(a2[hd]) + e2 * jraw[idx] / denj[t]) * inv;
  comb[idx] = f2bf(v);
}

// ---------------------------------------------------------------------------
// Branch 2 scores: proven structure (float4 wr, 512 blocks) with bf16 xT.
// rpart: (16 e-chunks, H, T).
// ---------------------------------------------------------------------------
__global__ __launch_bounds__(256) void rscore6(
    const ushort* __restrict__ xTbf, const float* __restrict__ wr,
    float* __restrict__ rpart, int T, int E)
{
  const int h = blockIdx.y;
  const int e0 = blockIdx.z * 64;
  const int t0 = (blockIdx.x * 256 + threadIdx.x) * 4;
  const float* wrh = wr + (size_t)h * E * T;
  float4 acc = {0.f, 0.f, 0.f, 0.f};
#pragma unroll 4
  for (int e = e0; e < e0 + 64; ++e) {
    ushort4v xv = *(const ushort4v*)(xTbf + (size_t)e * T + t0);
    float4 wv = *(const float4*)(wrh + (size_t)e * T + t0);
    acc.x += bf2f(xv.x) * wv.x;
    acc.y += bf2f(xv.y) * wv.y;
    acc.z += bf2f(xv.z) * wv.z;
    acc.w += bf2f(xv.w) * wv.w;
  }
  *(float4*)(rpart + ((size_t)blockIdx.z * HH + h) * T + t0) = acc;
}

// ---------------------------------------------------------------------------
// Fused janus_w + rsoftmax2 in ONE dispatch (disjoint block ranges, no
// inter-block dependence). Blocks [0,T): janus W row q. Blocks [T,T+H):
// branch-2 softmax for head h = bx - T.
// ---------------------------------------------------------------------------
__global__ __launch_bounds__(256) void jw_rsm(
    const float* __restrict__ snorm, ushort* __restrict__ Wb,
    float* __restrict__ den, const float* __restrict__ rpart,
    float* __restrict__ wwb, int T)
{
  __shared__ float rs[TT];
  __shared__ float red[4];
  if ((int)blockIdx.x < T) {
    const int q = blockIdx.x;
    const float sq = snorm[q] * 0.03125f;
    float mx = -1e30f;
    for (int k = threadIdx.x; k <= q; k += 256)
      mx = fmaxf(mx, sq * (snorm[k] * 0.03125f));
#pragma unroll
    for (int o = 32; o; o >>= 1) mx = fmaxf(mx, __shfl_xor(mx, o));
    if ((threadIdx.x & 63) == 0) red[threadIdx.x >> 6] = mx;
    __syncthreads();
    mx = fmaxf(fmaxf(red[0], red[1]), fmaxf(red[2], red[3]));
    float sum = 0.f;
    ushort* Wq = Wb + (size_t)q * T;
    for (int k = threadIdx.x; k < T; k += 256) {
      float wv = (k <= q) ? __expf(sq * (snorm[k] * 0.03125f) - mx) : 0.f;
      ushort wb = f2bf(wv);
      Wq[k] = wb;
      sum += bf2f(wb);
    }
#pragma unroll
    for (int o = 32; o; o >>= 1) sum += __shfl_xor(sum, o);
    __syncthreads();
    if ((threadIdx.x & 63) == 0) red[threadIdx.x >> 6] = sum;
    __syncthreads();
    if (threadIdx.x == 0) den[q] = red[0] + red[1] + red[2] + red[3];
  } else {
    const int h = blockIdx.x - T;
    for (int t = threadIdx.x; t < T; t += 256) {
      float a = 0.f;
#pragma unroll
      for (int s = 0; s < 16; ++s) a += rpart[((size_t)s * HH + h) * T + t];
      rs[t] = a;
    }
    __syncthreads();
    float mx = -1e30f;
    for (int t = threadIdx.x; t < T; t += 256) mx = fmaxf(mx, rs[t]);
#pragma unroll
    for (int o = 32; o; o >>= 1) mx = fmaxf(mx, __shfl_xor(mx, o));
    if ((threadIdx.x & 63) == 0) red[threadIdx.x >> 6] = mx;
    __syncthreads();
    mx = fmaxf(fmaxf(red[0], red[1]), fmaxf(red[2], red[3]));
    float* wh = wwb + (size_t)h * T;
    for (int t = threadIdx.x; t < T; t += 256)
      wh[t] = __expf((rs[t] - mx) * 0.125f);
  }
}

// ---------------------------------------------------------------------------
// RRP prefix scan, two passes, LDS-staged wide loads (G13 fix).
// grid (H,32) x 64 threads. Each block stages its 64k x 64d rv tile (8 KB)
// with short8 loads, computes from LDS; scan2 also buffers output in LDS
// and flushes with short8 stores. No inter-block sync.
// ---------------------------------------------------------------------------
__global__ __launch_bounds__(64) void rrp_part(
    const float* __restrict__ wgt, const ushort* __restrict__ rv,
    float* __restrict__ segsum, int T)
{
  const int h = blockIdx.x, seg = blockIdx.y, d = threadIdx.x;
  const int segLen = T >> 5;  // 64
  const int kbeg = seg * segLen;
  __shared__ __align__(16) ushort rvs[64 * 64];
  __shared__ float wls[64];
  wls[d] = wgt[(size_t)h * T + kbeg + d];
  {
    const short8* src = (const short8*)(rv + (size_t)h * T * 64 +
                                        (size_t)kbeg * 64);
    short8* dst = (short8*)rvs;
#pragma unroll
    for (int j = 0; j < 8; ++j) dst[j * 64 + d] = src[j * 64 + d];
  }
  __syncthreads();
  float num = 0.f, den = 0.f;
  for (int k = 0; k < segLen; ++k) {
    float wk = wls[k];
    num += wk * bf2f(rvs[k * 64 + d]);
    den += wk;
  }
  float* o = segsum + ((size_t)h * 32 + seg) * 65;
  o[d] = num;
  if (d == 0) o[64] = den;
}

__global__ __launch_bounds__(64) void rrp_scan2(
    const float* __restrict__ wgt, const ushort* __restrict__ rv,
    const float* __restrict__ segsum, ushort* __restrict__ out, int T)
{
  const int h = blockIdx.x, seg = blockIdx.y, d = threadIdx.x;
  const int segLen = T >> 5;  // 64
  const int kbeg = seg * segLen;
  __shared__ __align__(16) ushort rvs[64 * 64];
  __shared__ float wls[64];
  wls[d] = wgt[(size_t)h * T + kbeg + d];
  {
    const short8* src = (const short8*)(rv + (size_t)h * T * 64 +
                                        (size_t)kbeg * 64);
    short8* dst = (short8*)rvs;
#pragma unroll
    for (int j = 0; j < 8; ++j) dst[j * 64 + d] = src[j * 64 + d];
  }
  float num = 0.f, den = 0.f;
  for (int s = 0; s < seg; ++s) {
    const float* p = segsum + ((size_t)h * 32 + s) * 65;
    num += p[d];
    den += p[64];
  }
  __syncthreads();
  for (int k = 0; k < segLen; ++k) {
    float wk = wls[k];
    num += wk * bf2f(rvs[k * 64 + d]);
    den += wk;
    rvs[k * 64 + d] = f2bf(num / den);
  }
  __syncthreads();
  {
    short8* dst = (short8*)(out + (size_t)h * T * 64 + (size_t)kbeg * 64);
    const short8* src = (const short8*)rvs;
#pragma unroll
    for (int j = 0; j < 8; ++j) dst[j * 64 + d] = src[j * 64 + d];
  }
}

// ---------------------------------------------------------------------------
extern "C" void kernel_launch(void* const* d_in, const int* in_sizes, int n_in,
                              void* d_out, int out_size, void* d_ws, size_t ws_size,
                              hipStream_t stream)
{
  (void)in_sizes; (void)n_in; (void)out_size; (void)ws_size;
  const float* x    = (const float*)d_in[0];
  const float* wq   = (const float*)d_in[1];
  const float* wk   = (const float*)d_in[2];
  const float* wv   = (const float*)d_in[3];
  const float* wr   = (const float*)d_in[4];
  const float* wvr  = (const float*)d_in[5];
  const float* wj   = (const float*)d_in[6];
  const float* gate = (const float*)d_in[7];
  const float* wo   = (const float*)d_in[8];
  float* out = (float*)d_out;

  const int T = TT, E = EE, H = HH;
  const int nqt = T / 64;
  const size_t TE = (size_t)T * E;
  const size_t EE2 = (size_t)E * E;
  const size_t TT2 = (size_t)T * T;

  ushort* u = (ushort*)d_ws;
  ushort* xbf   = u;
  ushort* xh    = xbf + TE;
  ushort* xTbf  = xh + TE;        // (E,T) bf16
  ushort* wqb   = xTbf + TE;
  ushort* wkb   = wqb + EE2;
  ushort* wvb   = wkb + EE2;
  ushort* wvrb  = wvb + EE2;
  ushort* wob   = wvrb + EE2;
  ushort* wjh   = wob + EE2;
  ushort* qhb   = wjh + EE2;      // (H,T,64) bf16
  ushort* khb   = qhb + TE;       // (H,T,64) bf16
  ushort* vtb   = khb + TE;       // (H,64,T) f16
  ushort* rvhb  = vtb + TE;       // (H,T,64) bf16
  ushort* echoT = rvhb + TE;      // (E,T)    bf16
  ushort* a1b   = echoT + TE;     // (H,T,64) bf16
  ushort* a2b   = a1b + TE;       // (H,T,64) bf16
  ushort* Wbf   = a2b + TE;       // (T,T)    bf16
  ushort* combb = Wbf + TT2;      // (T,E)    bf16
  float* jraw   = (float*)(combb + TE);   // (T,E) fp32
  float* wwb    = jraw + TE;              // (H,T)
  float* snorm  = wwb + (size_t)H * T;    // (T)
  float* denj   = snorm + T;              // (T)
  float* rpart  = denj + T;               // (16,H,T)
  float* segsum = rpart + (size_t)16 * H * T;   // (H,32,65)

  dim3 blk(256);
  // all input conversions in ONE dispatch (also zeroes snorm)
  cvt_all<<<dim3(E / 32, T / 32, 7), blk, 0, stream>>>(
      x, xbf, xh, xTbf, wq, wk, wv, wvr, wo, wj,
      wqb, wkb, wvb, wvrb, wob, wjh, snorm);

  // 4 bf16 projections + echo(f16) in one dispatch (dbuf + swizzled LDS)
  proj5<<<dim3(E / 128, T / 128, 5), blk, 0, stream>>>(
      xbf, xh, wqb, wkb, wvb, wvrb, wjh,
      qhb, khb, vtb, rvhb, echoT, snorm, T, E, E);

  // branch 2 scores (bf16 xT + f32 wr)
  rscore6<<<dim3(T / 1024, H, E / 64), blk, 0, stream>>>(
      xTbf, wr, rpart, T, E);

  // fused janus W + branch-2 softmax (one dispatch)
  jw_rsm<<<T + H, blk, 0, stream>>>(snorm, Wbf, denj, rpart, wwb, T);

  // branch 1: flash, no split, normalized bf16 output (no merge pass)
  flash_mfma<<<dim3(H * nqt * 4), dim3(64), 0, stream>>>(
      qhb, khb, vtb, a1b, T, nqt);

  // branch 2: prefix scan (2-pass, LDS-staged wide loads)
  rrp_part<<<dim3(H, 32), dim3(64), 0, stream>>>(wwb, rvhb, segsum, T);
  rrp_scan2<<<dim3(H, 32), dim3(64), 0, stream>>>(wwb, rvhb, segsum, a2b, T);

  // branch 3 causal GEMM
  gemm_mfma<true><<<dim3(E / 128, T / 128), blk, 0, stream>>>(
      Wbf, echoT, jraw, T, E, T);

  // gated combine, then output projection
  combine_kernel<<<(int)(TE / 256), blk, 0, stream>>>(a1b, a2b, jraw, denj,
                                                      gate, combb, T);
  gemm_mfma<false><<<dim3(E / 128, T / 128), blk, 0, stream>>>(
      combb, wob, (float*)out, T, E, E);
}

// Round 9
// 407.195 us; speedup vs baseline: 1.3875x; 1.0222x over previous
//
#include <hip/hip_runtime.h>
#include <cstddef>
#include <cstdint>

#define TT 2048
#define EE 1024
#define HH 16

typedef unsigned short ushort;
typedef unsigned int uint;
typedef __attribute__((ext_vector_type(8))) short short8;
typedef __attribute__((ext_vector_type(8))) _Float16 half8;
typedef __attribute__((ext_vector_type(4))) float f32x4;
typedef __attribute__((ext_vector_type(4))) ushort ushort4v;

__device__ __forceinline__ ushort f2bf(float f) {
  uint u = __builtin_bit_cast(uint, f);
  u = (u + 0x7FFFu + ((u >> 16) & 1u)) >> 16;
  return (ushort)u;
}
__device__ __forceinline__ float bf2f(ushort h) {
  return __builtin_bit_cast(float, (uint)h << 16);
}
__device__ __forceinline__ ushort f2h(float f) {
  return __builtin_bit_cast(ushort, (_Float16)f);
}

// async global->LDS, 16B per lane; lds dest = wave-uniform base + lane*16
__device__ __forceinline__ void async16(ushort* lds, const ushort* g) {
  __builtin_amdgcn_global_load_lds(
      reinterpret_cast<const __attribute__((address_space(1))) void*>(
          reinterpret_cast<uintptr_t>(g)),
      reinterpret_cast<__attribute__((address_space(3))) void*>(
          static_cast<unsigned int>(reinterpret_cast<uintptr_t>(lds))),
      16, 0, 0);
}

// ---------------------------------------------------------------------------
// Fused conversions (one dispatch, NO inter-block sync):
// z=0: x (T,E) fp32 -> xbf (bf16), xh (f16), xTbf (E,T bf16); zeroes snorm
//      in block (0,0).
// z=1..6: weight converts (wq,wk,wv,wvr,wo->bf16; wj->f16), linear blocks.
// ---------------------------------------------------------------------------
__global__ __launch_bounds__(256) void cvt_all(
    const float* __restrict__ x, ushort* __restrict__ xbf,
    ushort* __restrict__ xh, ushort* __restrict__ xTbf,
    const float* __restrict__ w0, const float* __restrict__ w1,
    const float* __restrict__ w2, const float* __restrict__ w3,
    const float* __restrict__ w4, const float* __restrict__ w5,
    ushort* __restrict__ d0, ushort* __restrict__ d1,
    ushort* __restrict__ d2, ushort* __restrict__ d3,
    ushort* __restrict__ d4, ushort* __restrict__ d5,
    float* __restrict__ snorm)
{
  const int z = blockIdx.z;
  if (z == 0) {
    __shared__ float tile[32][33];
    if (blockIdx.x == 0 && blockIdx.y == 0) {
      for (int i = threadIdx.x; i < TT; i += 256) snorm[i] = 0.f;
    }
    const int bn = blockIdx.x * 32;   // col base (E)
    const int bm = blockIdx.y * 32;   // row base (T)
    const int c4 = (threadIdx.x & 7) * 4;
    const int r  = threadIdx.x >> 3;  // 0..31
    const size_t off = (size_t)(bm + r) * EE + bn + c4;
    float4 v = *(const float4*)(x + off);
    tile[r][c4 + 0] = v.x; tile[r][c4 + 1] = v.y;
    tile[r][c4 + 2] = v.z; tile[r][c4 + 3] = v.w;
    ushort4v b, h;
    b.x = f2bf(v.x); b.y = f2bf(v.y); b.z = f2bf(v.z); b.w = f2bf(v.w);
    h.x = f2h(v.x);  h.y = f2h(v.y);  h.z = f2h(v.z);  h.w = f2h(v.w);
    *(ushort4v*)(xbf + off) = b;
    *(ushort4v*)(xh + off) = h;
    __syncthreads();
    const int t4 = (threadIdx.x & 7) * 4;   // t offset within tile
    const int e  = threadIdx.x >> 3;        // e offset within tile
    ushort4v tb;
    tb.x = f2bf(tile[t4 + 0][e]); tb.y = f2bf(tile[t4 + 1][e]);
    tb.z = f2bf(tile[t4 + 2][e]); tb.w = f2bf(tile[t4 + 3][e]);
    *(ushort4v*)(xTbf + (size_t)(bn + e) * TT + bm + t4) = tb;
    return;
  }
  const int lin = blockIdx.y * 32 + blockIdx.x;
  if (lin >= 1024) return;
  const float* src; ushort* dst;
  switch (z) {
    case 1: src = w0; dst = d0; break;
    case 2: src = w1; dst = d1; break;
    case 3: src = w2; dst = d2; break;
    case 4: src = w3; dst = d3; break;
    case 5: src = w4; dst = d4; break;
    default: src = w5; dst = d5; break;
  }
  const int i = lin * 1024 + threadIdx.x * 4;
  float4 v = *(const float4*)(src + i);
  ushort4v o;
  if (z == 6) {
    o.x = f2h(v.x); o.y = f2h(v.y); o.z = f2h(v.z); o.w = f2h(v.w);
  } else {
    o.x = f2bf(v.x); o.y = f2bf(v.y); o.z = f2bf(v.z); o.w = f2bf(v.w);
  }
  *(ushort4v*)(dst + i) = o;
}

// ---------------------------------------------------------------------------
// Merged 5-way projection GEMM (round-7 structure, unchanged):
//   BK=64, dbuf LDS, one barrier per K-step, XOR-swizzled LDS.
// z=0..3: bf16 x@W^T -> qhb/khb(OM1 bf16), vtb(OM2 f16), rvhb(OM1 bf16)
// z=4:    f16  xh@wjh^T -> echoT (E,T bf16, OM3) + snorm row norms
// ---------------------------------------------------------------------------
__global__ __launch_bounds__(256) void proj5(
    const ushort* __restrict__ Abf, const ushort* __restrict__ Ah,
    const ushort* __restrict__ B0, const ushort* __restrict__ B1,
    const ushort* __restrict__ B2, const ushort* __restrict__ B3,
    const ushort* __restrict__ B4,
    ushort* __restrict__ C0, ushort* __restrict__ C1,
    ushort* __restrict__ C2, ushort* __restrict__ C3,
    ushort* __restrict__ C4, float* __restrict__ snorm,
    int M, int N, int K)
{
  const ushort* A; const ushort* B; ushort* C; int om;
  switch (blockIdx.z) {
    case 0: A = Abf; B = B0; C = C0; om = 1; break;
    case 1: A = Abf; B = B1; C = C1; om = 1; break;
    case 2: A = Abf; B = B2; C = C2; om = 2; break;
    case 3: A = Abf; B = B3; C = C3; om = 1; break;
    default: A = Ah; B = B4; C = C4; om = 3; break;
  }
  const bool f16 = (blockIdx.z == 4);
  __shared__ __align__(16) ushort As[2][128 * 64];
  __shared__ __align__(16) ushort Bs[2][128 * 64];
  const int tid = threadIdx.x;
  const int m0 = blockIdx.y * 128, n0 = blockIdx.x * 128;
  const int w = tid >> 6, lane = tid & 63;
  const int wr = w >> 1, wc = w & 1;
  const int lr = lane & 15, lk = lane >> 4;
  const int srow = lane >> 3;                   // 0..7 within 8-row stripe
  const int scol = ((lane & 7) ^ srow) * 8;     // pre-swizzled source granule
  const ushort* AgL = A + (size_t)(m0 + w * 32 + srow) * K + scol;
  const ushort* BgL = B + (size_t)(n0 + w * 32 + srow) * K + scol;
  const int sbase = (w * 32) * 64;
  const int s0 = (lk ^ (lr & 7)) * 8;
  f32x4 acc[4][4] = {};
  const int NT = K >> 6;
#pragma unroll
  for (int c = 0; c < 4; ++c) {
    async16(&As[0][sbase + c * 8 * 64], AgL + (size_t)c * 8 * K);
    async16(&Bs[0][sbase + c * 8 * 64], BgL + (size_t)c * 8 * K);
  }
  __syncthreads();
  for (int kt = 0; kt < NT; ++kt) {
    const int cur = kt & 1;
    if (kt + 1 < NT) {
      const int kn = (kt + 1) << 6;
#pragma unroll
      for (int c = 0; c < 4; ++c) {
        async16(&As[cur ^ 1][sbase + c * 8 * 64], AgL + (size_t)c * 8 * K + kn);
        async16(&Bs[cur ^ 1][sbase + c * 8 * 64], BgL + (size_t)c * 8 * K + kn);
      }
    }
    short8 a0[4], a1[4], b0[4], b1[4];
#pragma unroll
    for (int i = 0; i < 4; ++i) {
      const ushort* p = &As[cur][(wr * 64 + i * 16 + lr) * 64];
      a0[i] = *(const short8*)(p + s0);
      a1[i] = *(const short8*)(p + (s0 ^ 32));
    }
#pragma unroll
    for (int j = 0; j < 4; ++j) {
      const ushort* p = &Bs[cur][(wc * 64 + j * 16 + lr) * 64];
      b0[j] = *(const short8*)(p + s0);
      b1[j] = *(const short8*)(p + (s0 ^ 32));
    }
    if (f16) {
#pragma unroll
      for (int i = 0; i < 4; ++i)
#pragma unroll
        for (int j = 0; j < 4; ++j) {
          acc[i][j] = __builtin_amdgcn_mfma_f32_16x16x32_f16(
              __builtin_bit_cast(half8, a0[i]), __builtin_bit_cast(half8, b0[j]),
              acc[i][j], 0, 0, 0);
          acc[i][j] = __builtin_amdgcn_mfma_f32_16x16x32_f16(
              __builtin_bit_cast(half8, a1[i]), __builtin_bit_cast(half8, b1[j]),
              acc[i][j], 0, 0, 0);
        }
    } else {
#pragma unroll
      for (int i = 0; i < 4; ++i)
#pragma unroll
        for (int j = 0; j < 4; ++j) {
          acc[i][j] = __builtin_amdgcn_mfma_f32_16x16x32_bf16(
              a0[i], b0[j], acc[i][j], 0, 0, 0);
          acc[i][j] = __builtin_amdgcn_mfma_f32_16x16x32_bf16(
              a1[i], b1[j], acc[i][j], 0, 0, 0);
        }
    }
    __syncthreads();
  }
#pragma unroll
  for (int i = 0; i < 4; ++i)
#pragma unroll
    for (int r = 0; r < 4; ++r) {
      int row = m0 + wr * 64 + i * 16 + lk * 4 + r;
#pragma unroll
      for (int j = 0; j < 4; ++j) {
        int col = n0 + wc * 64 + j * 16 + lr;
        ushort v = (om == 2) ? f2h(acc[i][j][r]) : f2bf(acc[i][j][r]);
        if (om == 1)
          C[((size_t)(col >> 6) * M + row) * 64 + (col & 63)] = v;
        else if (om == 2)
          C[(size_t)(col >> 6) * 64 * M + (size_t)(col & 63) * M + row] = v;
        else
          C[(size_t)col * M + row] = v;
      }
    }
  if (om == 3) {
#pragma unroll
    for (int i = 0; i < 4; ++i)
#pragma unroll
      for (int r = 0; r < 4; ++r) {
        float p = 0.f;
#pragma unroll
        for (int j = 0; j < 4; ++j) p += acc[i][j][r] * acc[i][j][r];
        p += __shfl_xor(p, 1); p += __shfl_xor(p, 2);
        p += __shfl_xor(p, 4); p += __shfl_xor(p, 8);
        if (lr == 0)
          atomicAdd(&snorm[m0 + wr * 64 + i * 16 + lk * 4 + r], p);
      }
  }
}

// ---------------------------------------------------------------------------
// Generic MFMA GEMM (output proj), fp32 out (round-7 structure, unchanged).
// ---------------------------------------------------------------------------
__global__ __launch_bounds__(256) void gemm_out(
    const ushort* __restrict__ A, const ushort* __restrict__ B,
    float* __restrict__ Cp, int M, int N, int K)
{
  __shared__ __align__(16) ushort As[2][128 * 64];
  __shared__ __align__(16) ushort Bs[2][128 * 64];
  const int tid = threadIdx.x;
  const int m0 = blockIdx.y * 128, n0 = blockIdx.x * 128;
  const int w = tid >> 6, lane = tid & 63;
  const int wr = w >> 1, wc = w & 1;
  const int lr = lane & 15, lk = lane >> 4;
  const int srow = lane >> 3;
  const int scol = ((lane & 7) ^ srow) * 8;
  const ushort* AgL = A + (size_t)(m0 + w * 32 + srow) * K + scol;
  const ushort* BgL = B + (size_t)(n0 + w * 32 + srow) * K + scol;
  const int sbase = (w * 32) * 64;
  const int s0 = (lk ^ (lr & 7)) * 8;
  f32x4 acc[4][4] = {};
  const int NT = K >> 6;
#pragma unroll
  for (int c = 0; c < 4; ++c) {
    async16(&As[0][sbase + c * 8 * 64], AgL + (size_t)c * 8 * K);
    async16(&Bs[0][sbase + c * 8 * 64], BgL + (size_t)c * 8 * K);
  }
  __syncthreads();
  for (int kt = 0; kt < NT; ++kt) {
    const int cur = kt & 1;
    if (kt + 1 < NT) {
      const int kn = (kt + 1) << 6;
#pragma unroll
      for (int c = 0; c < 4; ++c) {
        async16(&As[cur ^ 1][sbase + c * 8 * 64], AgL + (size_t)c * 8 * K + kn);
        async16(&Bs[cur ^ 1][sbase + c * 8 * 64], BgL + (size_t)c * 8 * K + kn);
      }
    }
    short8 a0[4], a1[4], b0[4], b1[4];
#pragma unroll
    for (int i = 0; i < 4; ++i) {
      const ushort* p = &As[cur][(wr * 64 + i * 16 + lr) * 64];
      a0[i] = *(const short8*)(p + s0);
      a1[i] = *(const short8*)(p + (s0 ^ 32));
    }
#pragma unroll
    for (int j = 0; j < 4; ++j) {
      const ushort* p = &Bs[cur][(wc * 64 + j * 16 + lr) * 64];
      b0[j] = *(const short8*)(p + s0);
      b1[j] = *(const short8*)(p + (s0 ^ 32));
    }
#pragma unroll
    for (int i = 0; i < 4; ++i)
#pragma unroll
      for (int j = 0; j < 4; ++j) {
        acc[i][j] = __builtin_amdgcn_mfma_f32_16x16x32_bf16(
            a0[i], b0[j], acc[i][j], 0, 0, 0);
        acc[i][j] = __builtin_amdgcn_mfma_f32_16x16x32_bf16(
            a1[i], b1[j], acc[i][j], 0, 0, 0);
      }
    __syncthreads();
  }
#pragma unroll
  for (int i = 0; i < 4; ++i)
#pragma unroll
    for (int r = 0; r < 4; ++r) {
      int row = m0 + wr * 64 + i * 16 + lk * 4 + r;
#pragma unroll
      for (int j = 0; j < 4; ++j) {
        int col = n0 + wc * 64 + j * 16 + lr;
        Cp[(size_t)row * N + col] = acc[i][j][r];
      }
    }
}

// ---------------------------------------------------------------------------
// Janus causal GEMM with FUSED gated combine epilogue.
// Computes jraw = W @ echoT in registers (causal: skip k >= m0+128), then
// per element: comb = (g0*a1 + g1*a2 + g2*acc/denj[row]) (gate-softmaxed),
// written bf16 to comb (T,E). Head h = bx*2 + wc is thread-uniform.
// Removes the jraw buffer and the separate combine dispatch.
// ---------------------------------------------------------------------------
__global__ __launch_bounds__(256) void gemm_janus(
    const ushort* __restrict__ A, const ushort* __restrict__ B,
    const ushort* __restrict__ a1b, const ushort* __restrict__ a2b,
    const float* __restrict__ denj, const float* __restrict__ gate,
    ushort* __restrict__ comb, int M, int N, int K)
{
  __shared__ __align__(16) ushort As[2][128 * 64];
  __shared__ __align__(16) ushort Bs[2][128 * 64];
  const int tid = threadIdx.x;
  const int m0 = blockIdx.y * 128, n0 = blockIdx.x * 128;
  const int w = tid >> 6, lane = tid & 63;
  const int wr = w >> 1, wc = w & 1;
  const int lr = lane & 15, lk = lane >> 4;
  const int srow = lane >> 3;
  const int scol = ((lane & 7) ^ srow) * 8;
  const ushort* AgL = A + (size_t)(m0 + w * 32 + srow) * K + scol;
  const ushort* BgL = B + (size_t)(n0 + w * 32 + srow) * K + scol;
  const int sbase = (w * 32) * 64;
  const int s0 = (lk ^ (lr & 7)) * 8;
  f32x4 acc[4][4] = {};
  const int Keff = (K < m0 + 128) ? K : (m0 + 128);
  const int NT = Keff >> 6;
#pragma unroll
  for (int c = 0; c < 4; ++c) {
    async16(&As[0][sbase + c * 8 * 64], AgL + (size_t)c * 8 * K);
    async16(&Bs[0][sbase + c * 8 * 64], BgL + (size_t)c * 8 * K);
  }
  __syncthreads();
  for (int kt = 0; kt < NT; ++kt) {
    const int cur = kt & 1;
    if (kt + 1 < NT) {
      const int kn = (kt + 1) << 6;
#pragma unroll
      for (int c = 0; c < 4; ++c) {
        async16(&As[cur ^ 1][sbase + c * 8 * 64], AgL + (size_t)c * 8 * K + kn);
        async16(&Bs[cur ^ 1][sbase + c * 8 * 64], BgL + (size_t)c * 8 * K + kn);
      }
    }
    short8 a0[4], a1[4], b0[4], b1[4];
#pragma unroll
    for (int i = 0; i < 4; ++i) {
      const ushort* p = &As[cur][(wr * 64 + i * 16 + lr) * 64];
      a0[i] = *(const short8*)(p + s0);
      a1[i] = *(const short8*)(p + (s0 ^ 32));
    }
#pragma unroll
    for (int j = 0; j < 4; ++j) {
      const ushort* p = &Bs[cur][(wc * 64 + j * 16 + lr) * 64];
      b0[j] = *(const short8*)(p + s0);
      b1[j] = *(const short8*)(p + (s0 ^ 32));
    }
#pragma unroll
    for (int i = 0; i < 4; ++i)
#pragma unroll
      for (int j = 0; j < 4; ++j) {
        acc[i][j] = __builtin_amdgcn_mfma_f32_16x16x32_bf16(
            a0[i], b0[j], acc[i][j], 0, 0, 0);
        acc[i][j] = __builtin_amdgcn_mfma_f32_16x16x32_bf16(
            a1[i], b1[j], acc[i][j], 0, 0, 0);
      }
    __syncthreads();
  }
  // fused combine epilogue
  const int hA = blockIdx.x * 2 + wc;   // head for this thread's 64-col span
  const float g0 = gate[hA * 3 + 0], g1 = gate[hA * 3 + 1],
              g2 = gate[hA * 3 + 2];
  const float mg = fmaxf(g0, fmaxf(g1, g2));
  const float e0 = __expf(g0 - mg), e1 = __expf(g1 - mg),
              e2 = __expf(g2 - mg);
  const float inv = 1.f / (e0 + e1 + e2);
#pragma unroll
  for (int i = 0; i < 4; ++i)
#pragma unroll
    for (int r = 0; r < 4; ++r) {
      const int row = m0 + wr * 64 + i * 16 + lk * 4 + r;
      const float dj = e2 / denj[row];
#pragma unroll
      for (int j = 0; j < 4; ++j) {
        const int d = j * 16 + lr;
        const size_t hd = ((size_t)hA * M + row) * 64 + d;
        const float v =
            (e0 * bf2f(a1b[hd]) + e1 * bf2f(a2b[hd]) + dj * acc[i][j][r]) * inv;
        comb[(size_t)row * N + n0 + wc * 64 + d] = f2bf(v);
      }
    }
}

// ---------------------------------------------------------------------------
// Merged flash attention v9 + rrp_part in ONE 64-thread dispatch.
// Blocks [0,NF): flash (1-wave, no split-K, in-kernel normalization,
//   XCD head mapping, f16 P/V, hoisted causal mask).
// Blocks [NF, NF+H*32): rrp_part (LDS-staged wide loads).
// Shared LDS buffer aliased by both paths (wave-uniform branch).
// ---------------------------------------------------------------------------
__global__ __launch_bounds__(64) void flash_rrp(
    const ushort* __restrict__ Qg, const ushort* __restrict__ Kg,
    const ushort* __restrict__ Vg, ushort* __restrict__ O,
    const float* __restrict__ wgt, const ushort* __restrict__ rv,
    float* __restrict__ segsum, int T, int nqt, int NF)
{
  __shared__ __align__(16) ushort sbuf[64 * 64];
  __shared__ float wls[64];
  if ((int)blockIdx.x >= NF) {
    // ---- rrp_part ----
    const int bid = blockIdx.x - NF;
    const int h = bid >> 5, seg = bid & 31, d = threadIdx.x;
    const int segLen = T >> 5;  // 64
    const int kbeg = seg * segLen;
    wls[d] = wgt[(size_t)h * T + kbeg + d];
    {
      const short8* src = (const short8*)(rv + (size_t)h * T * 64 +
                                          (size_t)kbeg * 64);
      short8* dst = (short8*)sbuf;
#pragma unroll
      for (int j = 0; j < 8; ++j) dst[j * 64 + d] = src[j * 64 + d];
    }
    __syncthreads();
    float num = 0.f, den = 0.f;
    for (int k = 0; k < segLen; ++k) {
      float wk = wls[k];
      num += wk * bf2f(sbuf[k * 64 + d]);
      den += wk;
    }
    float* o = segsum + ((size_t)h * 32 + seg) * 65;
    o[d] = num;
    if (d == 0) o[64] = den;
    return;
  }
  // ---- flash ----
  const int bid = blockIdx.x;
  const int xcd = bid & 7;
  const int ii = bid >> 3;
  const int h = xcd * 2 + (ii & 1);       // 2 heads per XCD
  const int w  = (ii >> 1) & 3;           // q-strip within the 64-row q tile
  const int qt = (nqt - 1) - (ii >> 3);   // big q-tiles dispatched first
  const int q0 = qt * 64;
  const int ke = qt + 1;
  const int lane = threadIdx.x & 63;
  const int lr = lane & 15, lk = lane >> 4;
  const ushort* Q = Qg + (size_t)h * T * 64;
  const ushort* K = Kg + (size_t)h * T * 64;
  const ushort* V = Vg + (size_t)h * 64 * T;   // f16 bits
  ushort* Ps = sbuf;                            // 16*72 ushorts used
  const float CEXP = 0.18033688f;  // 0.125 * log2(e)

  f32x4 o[4] = {};
  float ls[4] = {0.f, 0.f, 0.f, 0.f};

  short8 qa0 = *(const short8*)(Q + (size_t)(q0 + w * 16 + lr) * 64 + lk * 8);
  short8 qa1 = *(const short8*)(Q + (size_t)(q0 + w * 16 + lr) * 64 + 32 + lk * 8);
  short8 kb0[4], kb1[4];
#pragma unroll
  for (int c = 0; c < 4; ++c) {
    const ushort* kp = K + (size_t)(c * 16 + lr) * 64 + lk * 8;
    kb0[c] = *(const short8*)kp;
    kb1[c] = *(const short8*)(kp + 32);
  }
  for (int kt = 0; kt < ke; ++kt) {
    const int k0 = kt * 64;
    short8 vb0[4], vb1[4];
#pragma unroll
    for (int c = 0; c < 4; ++c) {
      const ushort* vp = V + (size_t)(c * 16 + lr) * T + k0 + lk * 8;
      vb0[c] = *(const short8*)vp;
      vb1[c] = *(const short8*)(vp + 32);
    }
    f32x4 s[4];
    __builtin_amdgcn_s_setprio(1);
#pragma unroll
    for (int c = 0; c < 4; ++c) {
      f32x4 z = {};
      z = __builtin_amdgcn_mfma_f32_16x16x32_bf16(qa0, kb0[c], z, 0, 0, 0);
      z = __builtin_amdgcn_mfma_f32_16x16x32_bf16(qa1, kb1[c], z, 0, 0, 0);
      s[c] = z;
    }
    __builtin_amdgcn_s_setprio(0);
    if (kt + 1 < ke) {
#pragma unroll
      for (int c = 0; c < 4; ++c) {
        const ushort* kp = K + (size_t)(k0 + 64 + c * 16 + lr) * 64 + lk * 8;
        kb0[c] = *(const short8*)kp;
        kb1[c] = *(const short8*)(kp + 32);
      }
    }
    float pv[4][4];
#pragma unroll
    for (int c = 0; c < 4; ++c)
#pragma unroll
      for (int r = 0; r < 4; ++r)
        pv[c][r] = exp2f(s[c][r] * CEXP);
    if (kt == qt) {  // uniform branch: only the diagonal tile masks
      const int rowbase = q0 + w * 16 + lk * 4;
#pragma unroll
      for (int c = 0; c < 4; ++c) {
        const int col = k0 + c * 16 + lr;
#pragma unroll
        for (int r = 0; r < 4; ++r)
          if (col > rowbase + r) pv[c][r] = 0.f;
      }
    }
#pragma unroll
    for (int c = 0; c < 4; ++c)
#pragma unroll
      for (int r = 0; r < 4; ++r) {
        ls[r] += pv[c][r];
        Ps[(lk * 4 + r) * 72 + c * 16 + lr] = f2h(pv[c][r]);
      }
    short8 pa0 = *(const short8*)(&Ps[lr * 72 + lk * 8]);
    short8 pa1 = *(const short8*)(&Ps[lr * 72 + 32 + lk * 8]);
    __builtin_amdgcn_s_setprio(1);
#pragma unroll
    for (int c = 0; c < 4; ++c) {
      o[c] = __builtin_amdgcn_mfma_f32_16x16x32_f16(
          __builtin_bit_cast(half8, pa0), __builtin_bit_cast(half8, vb0[c]),
          o[c], 0, 0, 0);
      o[c] = __builtin_amdgcn_mfma_f32_16x16x32_f16(
          __builtin_bit_cast(half8, pa1), __builtin_bit_cast(half8, vb1[c]),
          o[c], 0, 0, 0);
    }
    __builtin_amdgcn_s_setprio(0);
  }
#pragma unroll
  for (int r = 0; r < 4; ++r) {
    ls[r] += __shfl_xor(ls[r], 1);
    ls[r] += __shfl_xor(ls[r], 2);
    ls[r] += __shfl_xor(ls[r], 4);
    ls[r] += __shfl_xor(ls[r], 8);
    ls[r] = 1.f / ls[r];
  }
  ushort* Oh = O + ((size_t)h * T + q0) * 64;
#pragma unroll
  for (int c = 0; c < 4; ++c)
#pragma unroll
    for (int r = 0; r < 4; ++r) {
      int row = w * 16 + lk * 4 + r;
      Oh[(size_t)row * 64 + c * 16 + lr] = f2bf(o[c][r] * ls[r]);
    }
}

// ---------------------------------------------------------------------------
// Branch 2 scores: proven structure (float4 wr, 512 blocks) with bf16 xT.
// rpart: (16 e-chunks, H, T).
// ---------------------------------------------------------------------------
__global__ __launch_bounds__(256) void rscore6(
    const ushort* __restrict__ xTbf, const float* __restrict__ wr,
    float* __restrict__ rpart, int T, int E)
{
  const int h = blockIdx.y;
  const int e0 = blockIdx.z * 64;
  const int t0 = (blockIdx.x * 256 + threadIdx.x) * 4;
  const float* wrh = wr + (size_t)h * E * T;
  float4 acc = {0.f, 0.f, 0.f, 0.f};
#pragma unroll 4
  for (int e = e0; e < e0 + 64; ++e) {
    ushort4v xv = *(const ushort4v*)(xTbf + (size_t)e * T + t0);
    float4 wv = *(const float4*)(wrh + (size_t)e * T + t0);
    acc.x += bf2f(xv.x) * wv.x;
    acc.y += bf2f(xv.y) * wv.y;
    acc.z += bf2f(xv.z) * wv.z;
    acc.w += bf2f(xv.w) * wv.w;
  }
  *(float4*)(rpart + ((size_t)blockIdx.z * HH + h) * T + t0) = acc;
}

// ---------------------------------------------------------------------------
// Fused janus_w + rsoftmax2 in ONE dispatch (disjoint block ranges).
// Blocks [0,T): janus W row q. Blocks [T,T+H): branch-2 softmax, h = bx - T.
// ---------------------------------------------------------------------------
__global__ __launch_bounds__(256) void jw_rsm(
    const float* __restrict__ snorm, ushort* __restrict__ Wb,
    float* __restrict__ den, const float* __restrict__ rpart,
    float* __restrict__ wwb, int T)
{
  __shared__ float rs[TT];
  __shared__ float red[4];
  if ((int)blockIdx.x < T) {
    const int q = blockIdx.x;
    const float sq = snorm[q] * 0.03125f;
    float mx = -1e30f;
    for (int k = threadIdx.x; k <= q; k += 256)
      mx = fmaxf(mx, sq * (snorm[k] * 0.03125f));
#pragma unroll
    for (int o = 32; o; o >>= 1) mx = fmaxf(mx, __shfl_xor(mx, o));
    if ((threadIdx.x & 63) == 0) red[threadIdx.x >> 6] = mx;
    __syncthreads();
    mx = fmaxf(fmaxf(red[0], red[1]), fmaxf(red[2], red[3]));
    float sum = 0.f;
    ushort* Wq = Wb + (size_t)q * T;
    for (int k = threadIdx.x; k < T; k += 256) {
      float wv = (k <= q) ? __expf(sq * (snorm[k] * 0.03125f) - mx) : 0.f;
      ushort wb = f2bf(wv);
      Wq[k] = wb;
      sum += bf2f(wb);
    }
#pragma unroll
    for (int o = 32; o; o >>= 1) sum += __shfl_xor(sum, o);
    __syncthreads();
    if ((threadIdx.x & 63) == 0) red[threadIdx.x >> 6] = sum;
    __syncthreads();
    if (threadIdx.x == 0) den[q] = red[0] + red[1] + red[2] + red[3];
  } else {
    const int h = blockIdx.x - T;
    for (int t = threadIdx.x; t < T; t += 256) {
      float a = 0.f;
#pragma unroll
      for (int s = 0; s < 16; ++s) a += rpart[((size_t)s * HH + h) * T + t];
      rs[t] = a;
    }
    __syncthreads();
    float mx = -1e30f;
    for (int t = threadIdx.x; t < T; t += 256) mx = fmaxf(mx, rs[t]);
#pragma unroll
    for (int o = 32; o; o >>= 1) mx = fmaxf(mx, __shfl_xor(mx, o));
    if ((threadIdx.x & 63) == 0) red[threadIdx.x >> 6] = mx;
    __syncthreads();
    mx = fmaxf(fmaxf(red[0], red[1]), fmaxf(red[2], red[3]));
    float* wh = wwb + (size_t)h * T;
    for (int t = threadIdx.x; t < T; t += 256)
      wh[t] = __expf((rs[t] - mx) * 0.125f);
  }
}

// ---------------------------------------------------------------------------
// RRP scan pass 2 (LDS-staged wide loads/stores, no inter-block sync).
// ---------------------------------------------------------------------------
__global__ __launch_bounds__(64) void rrp_scan2(
    const float* __restrict__ wgt, const ushort* __restrict__ rv,
    const float* __restrict__ segsum, ushort* __restrict__ out, int T)
{
  const int h = blockIdx.x, seg = blockIdx.y, d = threadIdx.x;
  const int segLen = T >> 5;  // 64
  const int kbeg = seg * segLen;
  __shared__ __align__(16) ushort rvs[64 * 64];
  __shared__ float wls[64];
  wls[d] = wgt[(size_t)h * T + kbeg + d];
  {
    const short8* src = (const short8*)(rv + (size_t)h * T * 64 +
                                        (size_t)kbeg * 64);
    short8* dst = (short8*)rvs;
#pragma unroll
    for (int j = 0; j < 8; ++j) dst[j * 64 + d] = src[j * 64 + d];
  }
  float num = 0.f, den = 0.f;
  for (int s = 0; s < seg; ++s) {
    const float* p = segsum + ((size_t)h * 32 + s) * 65;
    num += p[d];
    den += p[64];
  }
  __syncthreads();
  for (int k = 0; k < segLen; ++k) {
    float wk = wls[k];
    num += wk * bf2f(rvs[k * 64 + d]);
    den += wk;
    rvs[k * 64 + d] = f2bf(num / den);
  }
  __syncthreads();
  {
    short8* dst = (short8*)(out + (size_t)h * T * 64 + (size_t)kbeg * 64);
    const short8* src = (const short8*)rvs;
#pragma unroll
    for (int j = 0; j < 8; ++j) dst[j * 64 + d] = src[j * 64 + d];
  }
}

// ---------------------------------------------------------------------------
extern "C" void kernel_launch(void* const* d_in, const int* in_sizes, int n_in,
                              void* d_out, int out_size, void* d_ws, size_t ws_size,
                              hipStream_t stream)
{
  (void)in_sizes; (void)n_in; (void)out_size; (void)ws_size;
  const float* x    = (const float*)d_in[0];
  const float* wq   = (const float*)d_in[1];
  const float* wk   = (const float*)d_in[2];
  const float* wv   = (const float*)d_in[3];
  const float* wr   = (const float*)d_in[4];
  const float* wvr  = (const float*)d_in[5];
  const float* wj   = (const float*)d_in[6];
  const float* gate = (const float*)d_in[7];
  const float* wo   = (const float*)d_in[8];
  float* out = (float*)d_out;

  const int T = TT, E = EE, H = HH;
  const int nqt = T / 64;
  const size_t TE = (size_t)T * E;
  const size_t EE2 = (size_t)E * E;
  const size_t TT2 = (size_t)T * T;

  ushort* u = (ushort*)d_ws;
  ushort* xbf   = u;
  ushort* xh    = xbf + TE;
  ushort* xTbf  = xh + TE;        // (E,T) bf16
  ushort* wqb   = xTbf + TE;
  ushort* wkb   = wqb + EE2;
  ushort* wvb   = wkb + EE2;
  ushort* wvrb  = wvb + EE2;
  ushort* wob   = wvrb + EE2;
  ushort* wjh   = wob + EE2;
  ushort* qhb   = wjh + EE2;      // (H,T,64) bf16
  ushort* khb   = qhb + TE;       // (H,T,64) bf16
  ushort* vtb   = khb + TE;       // (H,64,T) f16
  ushort* rvhb  = vtb + TE;       // (H,T,64) bf16
  ushort* echoT = rvhb + TE;      // (E,T)    bf16
  ushort* a1b   = echoT + TE;     // (H,T,64) bf16
  ushort* a2b   = a1b + TE;       // (H,T,64) bf16
  ushort* Wbf   = a2b + TE;       // (T,T)    bf16
  ushort* combb = Wbf + TT2;      // (T,E)    bf16
  float* wwb    = (float*)(combb + TE);   // (H,T)
  float* snorm  = wwb + (size_t)H * T;    // (T)
  float* denj   = snorm + T;              // (T)
  float* rpart  = denj + T;               // (16,H,T)
  float* segsum = rpart + (size_t)16 * H * T;   // (H,32,65)

  dim3 blk(256);
  // all input conversions in ONE dispatch (also zeroes snorm)
  cvt_all<<<dim3(E / 32, T / 32, 7), blk, 0, stream>>>(
      x, xbf, xh, xTbf, wq, wk, wv, wvr, wo, wj,
      wqb, wkb, wvb, wvrb, wob, wjh, snorm);

  // 4 bf16 projections + echo(f16) in one dispatch (dbuf + swizzled LDS)
  proj5<<<dim3(E / 128, T / 128, 5), blk, 0, stream>>>(
      xbf, xh, wqb, wkb, wvb, wvrb, wjh,
      qhb, khb, vtb, rvhb, echoT, snorm, T, E, E);

  // branch 2 scores (bf16 xT + f32 wr)
  rscore6<<<dim3(T / 1024, H, E / 64), blk, 0, stream>>>(
      xTbf, wr, rpart, T, E);

  // fused janus W + branch-2 softmax (one dispatch)
  jw_rsm<<<T + H, blk, 0, stream>>>(snorm, Wbf, denj, rpart, wwb, T);

  // merged: flash (normalized bf16 out) + rrp_part, one 64-thread dispatch
  const int NF = H * nqt * 4;
  flash_rrp<<<dim3(NF + H * 32), dim3(64), 0, stream>>>(
      qhb, khb, vtb, a1b, wwb, rvhb, segsum, T, nqt, NF);

  // rrp scan pass 2
  rrp_scan2<<<dim3(H, 32), dim3(64), 0, stream>>>(wwb, rvhb, segsum, a2b, T);

  // janus causal GEMM with fused gated-combine epilogue -> combb
  gemm_janus<<<dim3(E / 128, T / 128), blk, 0, stream>>>(
      Wbf, echoT, a1b, a2b, denj, gate, combb, T, E, T);

  // output projection
  gemm_out<<<dim3(E / 128, T / 128), blk, 0, stream>>>(
      combb, wob, (float*)out, T, E, E);
}